// Round 17
// baseline (49.552 us; speedup 1.0000x reference)
//
#include <hip/hip_runtime.h>

typedef unsigned int u32;
typedef __fp16 h2v __attribute__((ext_vector_type(2)));
typedef __fp16 h4 __attribute__((ext_vector_type(4)));
typedef float f32x16 __attribute__((ext_vector_type(16)));

#define NB 256
#define NNODE 256
#define FF 128
#define DD 8
#define HDIM 32

__device__ __forceinline__ float dot2(h2v a, h2v b, float c) {
  return __builtin_amdgcn_fdot2(a, b, c, false);
}
__device__ __forceinline__ h2v bch2(u32 u) { return __builtin_bit_cast(h2v, u); }
__device__ __forceinline__ h4 bch4(uint2 u) { return __builtin_bit_cast(h4, u); }
__device__ __forceinline__ u32 bcu(h2v v) { return __builtin_bit_cast(u32, v); }
__device__ __forceinline__ f32x16 fzero() {
  f32x16 z;
  #pragma unroll
  for (int r = 0; r < 16; ++r) z[r] = 0.f;
  return z;
}
__device__ __forceinline__ f32x16 mfma8(h4 a, h4 b, f32x16 c) {
  return __builtin_amdgcn_mfma_f32_32x32x8f16(a, b, c, 0, 0, 0);
}

// -------- prep: W pack + bias + woT2 + edge scatter (mask pre-zeroed) ----------
__global__ __launch_bounds__(256) void prep_kernel(
    const float* __restrict__ Wq, const float* __restrict__ bq,
    const float* __restrict__ Wk, const float* __restrict__ bk,
    const float* __restrict__ Wv, const float* __restrict__ bv,
    const float* __restrict__ Wo, const int* __restrict__ eidx, int E,
    u32* __restrict__ mask, u32* __restrict__ WtH, float* __restrict__ bias,
    u32* __restrict__ woT2)
{
  int g = blockIdx.x * 256 + threadIdx.x;
  if (g < 96 * 64) {                 // WtH[c][kp]: pack W[2kp][c], W[2kp+1][c]
    int c = g >> 6, f = (g & 63) * 2;
    const float* W = (c < 32) ? Wq : ((c < 64) ? Wk : Wv);
    int cc = c & 31;
    WtH[g] = bcu(__builtin_amdgcn_cvt_pkrtz(W[f*HDIM + cc], W[(f+1)*HDIM + cc]));
  }
  if (g < 96) {
    const float* bb = (g < 32) ? bq : ((g < 64) ? bk : bv);
    bias[g] = bb[g & 31];
  }
  if (g < 128) {                     // woT2[d][p] = pack Wo[2p][d], Wo[2p+1][d]
    int d = g >> 4, p = g & 15;
    woT2[g] = bcu(__builtin_amdgcn_cvt_pkrtz(Wo[(2*p)*DD + d], Wo[(2*p+1)*DD + d]));
  }
  if (g < E) {
    int r = eidx[g], c = eidx[E + g];
    atomicOr(&mask[r*8 + (c >> 5)], 1u << (c & 31));
  }
}

// -------- fused: 2 blocks/batch, 4 waves; LDS overlay -> 3 blocks/CU -----------
// Phase A: smemU = wLds [96][66] u32 (25.3 KB).
// Phase B: smemU = kS [256][36] f16 (18 KB) + vt32 [32][260] f16 (16.6 KB).
__global__ __launch_bounds__(256, 3) void fused_kernel(
    const float* __restrict__ x, const u32* __restrict__ WtH,
    const float* __restrict__ bias, const u32* __restrict__ mask,
    const u32* __restrict__ woT2, const float* __restrict__ bo,
    float* __restrict__ out)
{
  __shared__ u32 smemU[8768];          // 35 KB overlaid
  __shared__ __fp16 oS[128 * 36];      // 9 KB, own q-rows
  __shared__ u32 woS[128];
  __shared__ float boS[8];
  u32* wLds = smemU;                   // phase A
  __fp16* kS = (__fp16*)smemU;         // phase B
  __fp16* vt32 = (__fp16*)smemU + 9216;

  int t = threadIdx.x, lane = t & 63, w = t >> 6;   // 4 waves
  int l31 = lane & 31, hi = lane >> 5;
  int b = blockIdx.x >> 1, half = blockIdx.x & 1;

  // stage W (coalesced global read, strided LDS write)
  for (int g = t; g < 96 * 64; g += 256)
    wLds[(g >> 6) * 66 + (g & 63)] = WtH[g];
  if (t < 128) woS[t] = woT2[t];
  if (t < 8) boS[t] = bo[t];

  // accumulator init
  f32x16 aq, ak0, av0, ak1, av1;
  #pragma unroll
  for (int r = 0; r < 16; ++r) aq[r] = bias[(r & 3) + 8*(r >> 2) + 4*hi];
  {
    float bk_ = bias[32 + l31], bv_ = bias[64 + l31];
    #pragma unroll
    for (int r = 0; r < 16; ++r) { ak0[r]=bk_; av0[r]=bv_; ak1[r]=bk_; av1[r]=bv_; }
  }

  // adjacency words for own q-row (issued early; overlaps W-stage latency)
  int node = half*128 + w*32 + l31;
  uint4 m0 = *(const uint4*)(mask + node * 8);
  uint4 m1 = *(const uint4*)(mask + node * 8 + 4);
  u32 mw8[8] = { m0.x, m0.y, m0.z, m0.w, m1.x, m1.y, m1.z, m1.w };
  #pragma unroll
  for (int i = 0; i < 8; ++i) mw8[i] = hi ? (mw8[i] >> 4) : mw8[i];

  __syncthreads();                     // wLds ready

  // ---- QKV: merged dual-tile loop; wave w -> tiles w and w+4 ----
  const float* xr0 = x + ((size_t)b * NNODE + w*32 + l31) * FF + 4 * hi;
  const float* xr1 = xr0 + (size_t)128 * FF;
  #pragma unroll
  for (int ks = 0; ks < 16; ++ks) {
    float4 xf0 = *(const float4*)(xr0 + ks * 8);
    float4 xf1 = *(const float4*)(xr1 + ks * 8);
    h2v a0 = __builtin_amdgcn_cvt_pkrtz(xf0.x, xf0.y);
    h2v b0 = __builtin_amdgcn_cvt_pkrtz(xf0.z, xf0.w);
    h4 f0 = __builtin_shufflevector(a0, b0, 0, 1, 2, 3);
    h2v a1 = __builtin_amdgcn_cvt_pkrtz(xf1.x, xf1.y);
    h2v b1 = __builtin_amdgcn_cvt_pkrtz(xf1.z, xf1.w);
    h4 f1 = __builtin_shufflevector(a1, b1, 0, 1, 2, 3);
    h4 wk = bch4(*(const uint2*)&wLds[(32 + l31)*66 + ks*4 + 2*hi]);
    h4 wv = bch4(*(const uint2*)&wLds[(64 + l31)*66 + ks*4 + 2*hi]);
    h4 wq = bch4(*(const uint2*)&wLds[l31*66 + ks*4 + 2*hi]);
    ak0 = mfma8(f0, wk, ak0);          // k: lane=hd-col, regs=node-rows
    ak1 = mfma8(f1, wk, ak1);
    av0 = mfma8(f0, wv, av0);
    av1 = mfma8(f1, wv, av1);
    aq  = mfma8(wq, half ? f1 : f0, aq);   // q^T of own tile: lane=node, regs=hd
  }
  __syncthreads();                     // all waves done READING wLds -> overlay OK

  #pragma unroll
  for (int r = 0; r < 16; ++r) {
    int rc = (r & 3) + 8*(r >> 2) + 4*hi;
    int n0 = w*32 + rc, n1 = n0 + 128;
    kS[n0 * 36 + l31] = (__fp16)ak0[r];
    kS[n1 * 36 + l31] = (__fp16)ak1[r];
    vt32[l31 * 260 + n0] = (__fp16)av0[r];
    vt32[l31 * 260 + n1] = (__fp16)av1[r];
  }
  // Q B-frags straight from aq regs
  h4 Qf[4];
  #pragma unroll
  for (int h = 0; h < 4; ++h) {
    h2v qa = __builtin_amdgcn_cvt_pkrtz(aq[4*h],     aq[4*h + 1]);
    h2v qb = __builtin_amdgcn_cvt_pkrtz(aq[4*h + 2], aq[4*h + 3]);
    Qf[h] = __builtin_shufflevector(qa, qb, 0, 1, 2, 3);
  }
  __syncthreads();                     // kS/vt32 ready

  // ---- attention: 2 head-pair passes (live regs < 128 -> no spill) ----
  const float sc2 = 0.51006977f;       // (1/sqrt(8)) * log2(e)
  const h2v one2 = bch2(0x3C003C00u);  // (1.0h, 1.0h)
  #pragma unroll
  for (int hp = 0; hp < 2; ++hp) {
    int h0 = 2*hp, h1 = 2*hp + 1;
    f32x16 accO0 = fzero(), accO1 = fzero();
    float lp0 = 0.f, lp1 = 0.f;
    #pragma unroll
    for (int kt = 0; kt < 8; ++kt) {
      u32 mwh = mw8[kt];
      float mbv[16];
      #pragma unroll
      for (int r = 0; r < 16; ++r) {   // select on constants, shared across pair
        int bp = (r & 3) + 8*(r >> 2);
        mbv[r] = ((mwh >> bp) & 1u) ? -8.0f : -1e30f;
      }
      u32 pw0[8], pw1[8];
      {
        h4 Kf = bch4(*(const uint2*)&kS[(kt*32 + l31)*36 + 8*h0 + 4*hi]);
        f32x16 T = mfma8(Kf, Qf[h0], fzero());   // T[kr][q=l31]
        #pragma unroll
        for (int j = 0; j < 8; ++j) {
          float p0 = __builtin_amdgcn_exp2f(__builtin_fmaf(T[2*j],   sc2, mbv[2*j]));
          float p1 = __builtin_amdgcn_exp2f(__builtin_fmaf(T[2*j+1], sc2, mbv[2*j+1]));
          pw0[j] = bcu(__builtin_amdgcn_cvt_pkrtz(p0, p1));
          lp0 = dot2(bch2(pw0[j]), one2, lp0);
        }
      }
      {
        h4 Kf = bch4(*(const uint2*)&kS[(kt*32 + l31)*36 + 8*h1 + 4*hi]);
        f32x16 T = mfma8(Kf, Qf[h1], fzero());
        #pragma unroll
        for (int j = 0; j < 8; ++j) {
          float p0 = __builtin_amdgcn_exp2f(__builtin_fmaf(T[2*j],   sc2, mbv[2*j]));
          float p1 = __builtin_amdgcn_exp2f(__builtin_fmaf(T[2*j+1], sc2, mbv[2*j+1]));
          pw1[j] = bcu(__builtin_amdgcn_cvt_pkrtz(p0, p1));
          lp1 = dot2(bch2(pw1[j]), one2, lp1);
        }
      }
      __builtin_amdgcn_s_setprio(1);
      #pragma unroll
      for (int kk = 0; kk < 4; ++kk) {
        h4 va = bch4(*(const uint2*)&vt32[l31*260 + kt*32 + kk*8 + 4*hi]);
        accO0 = mfma8(va, bch4(make_uint2(pw0[2*kk], pw0[2*kk+1])), accO0);
        accO1 = mfma8(va, bch4(make_uint2(pw1[2*kk], pw1[2*kk+1])), accO1);
      }
      __builtin_amdgcn_s_setprio(0);
    }
    float lq0 = lp0 + __shfl_xor(lp0, 32);
    float lq1 = lp1 + __shfl_xor(lp1, 32);
    float inv0 = 1.0f / lq0, inv1 = 1.0f / lq1;
    h2v a0 = __builtin_amdgcn_cvt_pkrtz(accO0[4*h0]*inv0,   accO0[4*h0+1]*inv0);
    h2v a1 = __builtin_amdgcn_cvt_pkrtz(accO0[4*h0+2]*inv0, accO0[4*h0+3]*inv0);
    *(uint2*)&oS[(w*32 + l31)*36 + 8*h0 + 4*hi] = make_uint2(bcu(a0), bcu(a1));
    h2v c0 = __builtin_amdgcn_cvt_pkrtz(accO1[4*h1]*inv1,   accO1[4*h1+1]*inv1);
    h2v c1 = __builtin_amdgcn_cvt_pkrtz(accO1[4*h1+2]*inv1, accO1[4*h1+3]*inv1);
    *(uint2*)&oS[(w*32 + l31)*36 + 8*h1 + 4*hi] = make_uint2(bcu(c0), bcu(c1));
  }
  __syncthreads();

  // ---- proj: 2 threads per row; out = oS @ Wo + bo ----
  int pr = t >> 1, d4 = (t & 1) * 4;
  float r4[4] = { boS[d4], boS[d4+1], boS[d4+2], boS[d4+3] };
  #pragma unroll
  for (int p = 0; p < 16; ++p) {
    h2v o2 = bch2(*(const u32*)&oS[pr*36 + 2*p]);
    #pragma unroll
    for (int d = 0; d < 4; ++d)
      r4[d] = dot2(o2, bch2(woS[(d4 + d)*16 + p]), r4[d]);
  }
  float4 o = { r4[0], r4[1], r4[2], r4[3] };
  *(float4*)(out + ((size_t)b * NNODE + half*128 + pr) * DD + d4) = o;
}

extern "C" void kernel_launch(void* const* d_in, const int* in_sizes, int n_in,
                              void* d_out, int out_size, void* d_ws, size_t ws_size,
                              hipStream_t stream)
{
  const float* x  = (const float*)d_in[0];
  const int*   ei = (const int*)d_in[1];
  const float* Wq = (const float*)d_in[2];
  const float* bq = (const float*)d_in[3];
  const float* Wk = (const float*)d_in[4];
  const float* bk = (const float*)d_in[5];
  const float* Wv = (const float*)d_in[6];
  const float* bv = (const float*)d_in[7];
  const float* Wo = (const float*)d_in[8];
  const float* bo = (const float*)d_in[9];
  int E = in_sizes[1] / 2;

  char* ws = (char*)d_ws;
  u32*   mask = (u32*)(ws + 0);                 // 8 KB
  u32*   WtH  = (u32*)(ws + 8192);              // 24 KB: W^T[c][kp] f16-packed
  float* bias = (float*)(ws + 32768);           // 384 B
  u32*   woT2 = (u32*)(ws + 33280);             // 512 B

  hipMemsetAsync(mask, 0, NNODE * 8 * sizeof(u32), stream);
  int prep_work = (96*64 > E) ? 96*64 : E;
  prep_kernel<<<(prep_work + 255)/256, 256, 0, stream>>>(
      Wq, bq, Wk, bk, Wv, bv, Wo, ei, E, mask, WtH, bias, woT2);
  fused_kernel<<<NB * 2, 256, 0, stream>>>(x, WtH, bias, mask, woT2, bo,
                                           (float*)d_out);
}

// Round 18
// 49.423 us; speedup vs baseline: 1.0026x; 1.0026x over previous
//
#include <hip/hip_runtime.h>

typedef unsigned int u32;
typedef __fp16 h2v __attribute__((ext_vector_type(2)));
typedef __fp16 h4 __attribute__((ext_vector_type(4)));
typedef float f32x16 __attribute__((ext_vector_type(16)));

#define NB 256
#define NNODE 256
#define FF 128
#define DD 8
#define HDIM 32

__device__ __forceinline__ float dot2(h2v a, h2v b, float c) {
  return __builtin_amdgcn_fdot2(a, b, c, false);
}
__device__ __forceinline__ h2v bch2(u32 u) { return __builtin_bit_cast(h2v, u); }
__device__ __forceinline__ h4 bch4(uint2 u) { return __builtin_bit_cast(h4, u); }
__device__ __forceinline__ u32 bcu(h2v v) { return __builtin_bit_cast(u32, v); }
__device__ __forceinline__ f32x16 fzero() {
  f32x16 z;
  #pragma unroll
  for (int r = 0; r < 16; ++r) z[r] = 0.f;
  return z;
}
__device__ __forceinline__ f32x16 mfma8(h4 a, h4 b, f32x16 c) {
  return __builtin_amdgcn_mfma_f32_32x32x8f16(a, b, c, 0, 0, 0);
}

// -------- prep: W pack + bias + woT2 + edge scatter (mask pre-zeroed) ----------
__global__ __launch_bounds__(256) void prep_kernel(
    const float* __restrict__ Wq, const float* __restrict__ bq,
    const float* __restrict__ Wk, const float* __restrict__ bk,
    const float* __restrict__ Wv, const float* __restrict__ bv,
    const float* __restrict__ Wo, const int* __restrict__ eidx, int E,
    u32* __restrict__ mask, u32* __restrict__ WtH, float* __restrict__ bias,
    u32* __restrict__ woT2)
{
  int g = blockIdx.x * 256 + threadIdx.x;
  if (g < 96 * 64) {                 // WtH[c][kp]: pack W[2kp][c], W[2kp+1][c]
    int c = g >> 6, f = (g & 63) * 2;
    const float* W = (c < 32) ? Wq : ((c < 64) ? Wk : Wv);
    int cc = c & 31;
    WtH[g] = bcu(__builtin_amdgcn_cvt_pkrtz(W[f*HDIM + cc], W[(f+1)*HDIM + cc]));
  }
  if (g < 96) {
    const float* bb = (g < 32) ? bq : ((g < 64) ? bk : bv);
    bias[g] = bb[g & 31];
  }
  if (g < 128) {                     // woT2[d][p] = pack Wo[2p][d], Wo[2p+1][d]
    int d = g >> 4, p = g & 15;
    woT2[g] = bcu(__builtin_amdgcn_cvt_pkrtz(Wo[(2*p)*DD + d], Wo[(2*p+1)*DD + d]));
  }
  if (g < E) {
    int r = eidx[g], c = eidx[E + g];
    atomicOr(&mask[r*8 + (c >> 5)], 1u << (c & 31));
  }
}

// -------- fused: 2 blocks/batch, 4 waves; LDS overlay -> 3 blocks/CU -----------
// Phase A: smemU = wLds [96][66] u32 (25.3 KB).
// Phase B: smemU = kS [256][36] f16 (18 KB) + vt32 [32][260] f16 (16.6 KB).
__global__ __launch_bounds__(256, 3) void fused_kernel(
    const float* __restrict__ x, const u32* __restrict__ WtH,
    const float* __restrict__ bias, const u32* __restrict__ mask,
    const u32* __restrict__ woT2, const float* __restrict__ bo,
    float* __restrict__ out)
{
  __shared__ u32 smemU[8768];          // 35 KB overlaid
  __shared__ __fp16 oS[128 * 36];      // 9 KB, own q-rows
  __shared__ u32 woS[128];
  __shared__ float boS[8];
  u32* wLds = smemU;                   // phase A
  __fp16* kS = (__fp16*)smemU;         // phase B
  __fp16* vt32 = (__fp16*)smemU + 9216;

  int t = threadIdx.x, lane = t & 63, w = t >> 6;   // 4 waves
  int l31 = lane & 31, hi = lane >> 5;
  int b = blockIdx.x >> 1, half = blockIdx.x & 1;

  // stage W (coalesced global read, strided LDS write)
  for (int g = t; g < 96 * 64; g += 256)
    wLds[(g >> 6) * 66 + (g & 63)] = WtH[g];
  if (t < 128) woS[t] = woT2[t];
  if (t < 8) boS[t] = bo[t];

  // accumulator init
  f32x16 aq, ak0, av0, ak1, av1;
  #pragma unroll
  for (int r = 0; r < 16; ++r) aq[r] = bias[(r & 3) + 8*(r >> 2) + 4*hi];
  {
    float bk_ = bias[32 + l31], bv_ = bias[64 + l31];
    #pragma unroll
    for (int r = 0; r < 16; ++r) { ak0[r]=bk_; av0[r]=bv_; ak1[r]=bk_; av1[r]=bv_; }
  }

  // adjacency words for own q-row (issued early; overlaps W-stage latency)
  int node = half*128 + w*32 + l31;
  uint4 m0 = *(const uint4*)(mask + node * 8);
  uint4 m1 = *(const uint4*)(mask + node * 8 + 4);
  u32 mw8[8] = { m0.x, m0.y, m0.z, m0.w, m1.x, m1.y, m1.z, m1.w };
  #pragma unroll
  for (int i = 0; i < 8; ++i) mw8[i] = hi ? (mw8[i] >> 4) : mw8[i];

  __syncthreads();                     // wLds ready

  // ---- QKV: merged dual-tile loop; wave w -> tiles w and w+4 ----
  const float* xr0 = x + ((size_t)b * NNODE + w*32 + l31) * FF + 4 * hi;
  const float* xr1 = xr0 + (size_t)128 * FF;
  #pragma unroll
  for (int ks = 0; ks < 16; ++ks) {
    float4 xf0 = *(const float4*)(xr0 + ks * 8);
    float4 xf1 = *(const float4*)(xr1 + ks * 8);
    h2v a0 = __builtin_amdgcn_cvt_pkrtz(xf0.x, xf0.y);
    h2v b0 = __builtin_amdgcn_cvt_pkrtz(xf0.z, xf0.w);
    h4 f0 = __builtin_shufflevector(a0, b0, 0, 1, 2, 3);
    h2v a1 = __builtin_amdgcn_cvt_pkrtz(xf1.x, xf1.y);
    h2v b1 = __builtin_amdgcn_cvt_pkrtz(xf1.z, xf1.w);
    h4 f1 = __builtin_shufflevector(a1, b1, 0, 1, 2, 3);
    h4 wk = bch4(*(const uint2*)&wLds[(32 + l31)*66 + ks*4 + 2*hi]);
    h4 wv = bch4(*(const uint2*)&wLds[(64 + l31)*66 + ks*4 + 2*hi]);
    h4 wq = bch4(*(const uint2*)&wLds[l31*66 + ks*4 + 2*hi]);
    ak0 = mfma8(f0, wk, ak0);          // k: lane=hd-col, regs=node-rows
    ak1 = mfma8(f1, wk, ak1);
    av0 = mfma8(f0, wv, av0);
    av1 = mfma8(f1, wv, av1);
    aq  = mfma8(wq, half ? f1 : f0, aq);   // q^T of own tile: lane=node, regs=hd
  }
  __syncthreads();                     // all waves done READING wLds -> overlay OK

  #pragma unroll
  for (int r = 0; r < 16; ++r) {
    int rc = (r & 3) + 8*(r >> 2) + 4*hi;
    int n0 = w*32 + rc, n1 = n0 + 128;
    kS[n0 * 36 + l31] = (__fp16)ak0[r];
    kS[n1 * 36 + l31] = (__fp16)ak1[r];
    vt32[l31 * 260 + n0] = (__fp16)av0[r];
    vt32[l31 * 260 + n1] = (__fp16)av1[r];
  }
  // Q B-frags straight from aq regs
  h4 Qf[4];
  #pragma unroll
  for (int h = 0; h < 4; ++h) {
    h2v qa = __builtin_amdgcn_cvt_pkrtz(aq[4*h],     aq[4*h + 1]);
    h2v qb = __builtin_amdgcn_cvt_pkrtz(aq[4*h + 2], aq[4*h + 3]);
    Qf[h] = __builtin_shufflevector(qa, qb, 0, 1, 2, 3);
  }
  __syncthreads();                     // kS/vt32 ready

  // ---- attention: 2 head-pair passes (live regs < 128 -> no spill) ----
  const float sc2 = 0.51006977f;       // (1/sqrt(8)) * log2(e)
  const h2v one2 = bch2(0x3C003C00u);  // (1.0h, 1.0h)
  #pragma unroll
  for (int hp = 0; hp < 2; ++hp) {
    int h0 = 2*hp, h1 = 2*hp + 1;
    f32x16 accO0 = fzero(), accO1 = fzero();
    float lp0 = 0.f, lp1 = 0.f;
    #pragma unroll
    for (int kt = 0; kt < 8; ++kt) {
      u32 mwh = mw8[kt];
      float mbv[16];
      #pragma unroll
      for (int r = 0; r < 16; ++r) {   // select on constants, shared across pair
        int bp = (r & 3) + 8*(r >> 2);
        mbv[r] = ((mwh >> bp) & 1u) ? -8.0f : -1e30f;
      }
      u32 pw0[8], pw1[8];
      {
        h4 Kf = bch4(*(const uint2*)&kS[(kt*32 + l31)*36 + 8*h0 + 4*hi]);
        f32x16 T = mfma8(Kf, Qf[h0], fzero());   // T[kr][q=l31]
        #pragma unroll
        for (int j = 0; j < 8; ++j) {
          float p0 = __builtin_amdgcn_exp2f(__builtin_fmaf(T[2*j],   sc2, mbv[2*j]));
          float p1 = __builtin_amdgcn_exp2f(__builtin_fmaf(T[2*j+1], sc2, mbv[2*j+1]));
          pw0[j] = bcu(__builtin_amdgcn_cvt_pkrtz(p0, p1));
          lp0 = dot2(bch2(pw0[j]), one2, lp0);
        }
      }
      {
        h4 Kf = bch4(*(const uint2*)&kS[(kt*32 + l31)*36 + 8*h1 + 4*hi]);
        f32x16 T = mfma8(Kf, Qf[h1], fzero());
        #pragma unroll
        for (int j = 0; j < 8; ++j) {
          float p0 = __builtin_amdgcn_exp2f(__builtin_fmaf(T[2*j],   sc2, mbv[2*j]));
          float p1 = __builtin_amdgcn_exp2f(__builtin_fmaf(T[2*j+1], sc2, mbv[2*j+1]));
          pw1[j] = bcu(__builtin_amdgcn_cvt_pkrtz(p0, p1));
          lp1 = dot2(bch2(pw1[j]), one2, lp1);
        }
      }
      __builtin_amdgcn_s_setprio(1);
      #pragma unroll
      for (int kk = 0; kk < 4; ++kk) {
        h4 va = bch4(*(const uint2*)&vt32[l31*260 + kt*32 + kk*8 + 4*hi]);
        accO0 = mfma8(va, bch4(make_uint2(pw0[2*kk], pw0[2*kk+1])), accO0);
        accO1 = mfma8(va, bch4(make_uint2(pw1[2*kk], pw1[2*kk+1])), accO1);
      }
      __builtin_amdgcn_s_setprio(0);
    }
    float lq0 = lp0 + __shfl_xor(lp0, 32);
    float lq1 = lp1 + __shfl_xor(lp1, 32);
    float inv0 = 1.0f / lq0, inv1 = 1.0f / lq1;
    h2v a0 = __builtin_amdgcn_cvt_pkrtz(accO0[4*h0]*inv0,   accO0[4*h0+1]*inv0);
    h2v a1 = __builtin_amdgcn_cvt_pkrtz(accO0[4*h0+2]*inv0, accO0[4*h0+3]*inv0);
    *(uint2*)&oS[(w*32 + l31)*36 + 8*h0 + 4*hi] = make_uint2(bcu(a0), bcu(a1));
    h2v c0 = __builtin_amdgcn_cvt_pkrtz(accO1[4*h1]*inv1,   accO1[4*h1+1]*inv1);
    h2v c1 = __builtin_amdgcn_cvt_pkrtz(accO1[4*h1+2]*inv1, accO1[4*h1+3]*inv1);
    *(uint2*)&oS[(w*32 + l31)*36 + 8*h1 + 4*hi] = make_uint2(bcu(c0), bcu(c1));
  }
  __syncthreads();

  // ---- proj: 2 threads per row; out = oS @ Wo + bo ----
  int pr = t >> 1, d4 = (t & 1) * 4;
  float r4[4] = { boS[d4], boS[d4+1], boS[d4+2], boS[d4+3] };
  #pragma unroll
  for (int p = 0; p < 16; ++p) {
    h2v o2 = bch2(*(const u32*)&oS[pr*36 + 2*p]);
    #pragma unroll
    for (int d = 0; d < 4; ++d)
      r4[d] = dot2(o2, bch2(woS[(d4 + d)*16 + p]), r4[d]);
  }
  float4 o = { r4[0], r4[1], r4[2], r4[3] };
  *(float4*)(out + ((size_t)b * NNODE + half*128 + pr) * DD + d4) = o;
}

extern "C" void kernel_launch(void* const* d_in, const int* in_sizes, int n_in,
                              void* d_out, int out_size, void* d_ws, size_t ws_size,
                              hipStream_t stream)
{
  const float* x  = (const float*)d_in[0];
  const int*   ei = (const int*)d_in[1];
  const float* Wq = (const float*)d_in[2];
  const float* bq = (const float*)d_in[3];
  const float* Wk = (const float*)d_in[4];
  const float* bk = (const float*)d_in[5];
  const float* Wv = (const float*)d_in[6];
  const float* bv = (const float*)d_in[7];
  const float* Wo = (const float*)d_in[8];
  const float* bo = (const float*)d_in[9];
  int E = in_sizes[1] / 2;

  char* ws = (char*)d_ws;
  u32*   mask = (u32*)(ws + 0);                 // 8 KB
  u32*   WtH  = (u32*)(ws + 8192);              // 24 KB: W^T[c][kp] f16-packed
  float* bias = (float*)(ws + 32768);           // 384 B
  u32*   woT2 = (u32*)(ws + 33280);             // 512 B

  hipMemsetAsync(mask, 0, NNODE * 8 * sizeof(u32), stream);
  int prep_work = (96*64 > E) ? 96*64 : E;
  prep_kernel<<<(prep_work + 255)/256, 256, 0, stream>>>(
      Wq, bq, Wk, bk, Wv, bv, Wo, ei, E, mask, WtH, bias, woT2);
  fused_kernel<<<NB * 2, 256, 0, stream>>>(x, WtH, bias, mask, woT2, bo,
                                           (float*)d_out);
}

// Round 19
// 48.851 us; speedup vs baseline: 1.0143x; 1.0117x over previous
//
#include <hip/hip_runtime.h>

typedef unsigned int u32;
typedef __fp16 h2v __attribute__((ext_vector_type(2)));
typedef __fp16 h4 __attribute__((ext_vector_type(4)));
typedef float f32x16 __attribute__((ext_vector_type(16)));

#define NB 256
#define NNODE 256
#define FF 128
#define DD 8
#define HDIM 32

__device__ __forceinline__ float dot2(h2v a, h2v b, float c) {
  return __builtin_amdgcn_fdot2(a, b, c, false);
}
__device__ __forceinline__ h2v bch2(u32 u) { return __builtin_bit_cast(h2v, u); }
__device__ __forceinline__ h4 bch4(uint2 u) { return __builtin_bit_cast(h4, u); }
__device__ __forceinline__ u32 bcu(h2v v) { return __builtin_bit_cast(u32, v); }
__device__ __forceinline__ f32x16 fzero() {
  f32x16 z;
  #pragma unroll
  for (int r = 0; r < 16; ++r) z[r] = 0.f;
  return z;
}
__device__ __forceinline__ f32x16 mfma8(h4 a, h4 b, f32x16 c) {
  return __builtin_amdgcn_mfma_f32_32x32x8f16(a, b, c, 0, 0, 0);
}

// -------- prep: W pack + bias + woT2 + edge scatter (mask pre-zeroed) ----------
__global__ __launch_bounds__(256) void prep_kernel(
    const float* __restrict__ Wq, const float* __restrict__ bq,
    const float* __restrict__ Wk, const float* __restrict__ bk,
    const float* __restrict__ Wv, const float* __restrict__ bv,
    const float* __restrict__ Wo, const int* __restrict__ eidx, int E,
    u32* __restrict__ mask, u32* __restrict__ WtH, float* __restrict__ bias,
    u32* __restrict__ woT2)
{
  int g = blockIdx.x * 256 + threadIdx.x;
  if (g < 96 * 64) {                 // WtH[c][kp]: pack W[2kp][c], W[2kp+1][c]
    int c = g >> 6, f = (g & 63) * 2;
    const float* W = (c < 32) ? Wq : ((c < 64) ? Wk : Wv);
    int cc = c & 31;
    WtH[g] = bcu(__builtin_amdgcn_cvt_pkrtz(W[f*HDIM + cc], W[(f+1)*HDIM + cc]));
  }
  if (g < 96) {
    const float* bb = (g < 32) ? bq : ((g < 64) ? bk : bv);
    bias[g] = bb[g & 31];
  }
  if (g < 128) {                     // woT2[d][p] = pack Wo[2p][d], Wo[2p+1][d]
    int d = g >> 4, p = g & 15;
    woT2[g] = bcu(__builtin_amdgcn_cvt_pkrtz(Wo[(2*p)*DD + d], Wo[(2*p+1)*DD + d]));
  }
  if (g < E) {
    int r = eidx[g], c = eidx[E + g];
    atomicOr(&mask[r*8 + (c >> 5)], 1u << (c & 31));
  }
}

// -------- fused: 2 blocks/batch, 4 waves; LDS overlay -> 3 blocks/CU -----------
// Phase A: smemU = wLds [96][66] u32 (25.3 KB).
// Phase B: smemU = kS [256][36] f16 (18 KB) + vt32 [32][260] f16 (16.6 KB).
__global__ __launch_bounds__(256, 3) void fused_kernel(
    const float* __restrict__ x, const u32* __restrict__ WtH,
    const float* __restrict__ bias, const u32* __restrict__ mask,
    const u32* __restrict__ woT2, const float* __restrict__ bo,
    float* __restrict__ out)
{
  __shared__ u32 smemU[8768];          // 35 KB overlaid
  __shared__ __fp16 oS[128 * 36];      // 9 KB, own q-rows
  __shared__ u32 woS[128];
  __shared__ float boS[8];
  u32* wLds = smemU;                   // phase A
  __fp16* kS = (__fp16*)smemU;         // phase B
  __fp16* vt32 = (__fp16*)smemU + 9216;

  int t = threadIdx.x, lane = t & 63, w = t >> 6;   // 4 waves
  int l31 = lane & 31, hi = lane >> 5;
  int b = blockIdx.x >> 1, half = blockIdx.x & 1;

  // stage W (coalesced global read, strided LDS write)
  for (int g = t; g < 96 * 64; g += 256)
    wLds[(g >> 6) * 66 + (g & 63)] = WtH[g];
  if (t < 128) woS[t] = woT2[t];
  if (t < 8) boS[t] = bo[t];

  // accumulator init
  f32x16 aq, ak0, av0, ak1, av1;
  #pragma unroll
  for (int r = 0; r < 16; ++r) aq[r] = bias[(r & 3) + 8*(r >> 2) + 4*hi];
  {
    float bk_ = bias[32 + l31], bv_ = bias[64 + l31];
    #pragma unroll
    for (int r = 0; r < 16; ++r) { ak0[r]=bk_; av0[r]=bv_; ak1[r]=bk_; av1[r]=bv_; }
  }

  // adjacency words for own q-row (issued early; overlaps W-stage latency)
  int node = half*128 + w*32 + l31;
  uint4 m0 = *(const uint4*)(mask + node * 8);
  uint4 m1 = *(const uint4*)(mask + node * 8 + 4);
  u32 mw8[8] = { m0.x, m0.y, m0.z, m0.w, m1.x, m1.y, m1.z, m1.w };
  #pragma unroll
  for (int i = 0; i < 8; ++i) mw8[i] = hi ? (mw8[i] >> 4) : mw8[i];

  __syncthreads();                     // wLds ready

  // ---- QKV: merged dual-tile loop; wave w -> tiles w and w+4 ----
  const float* xr0 = x + ((size_t)b * NNODE + w*32 + l31) * FF + 4 * hi;
  const float* xr1 = xr0 + (size_t)128 * FF;
  #pragma unroll
  for (int ks = 0; ks < 16; ++ks) {
    float4 xf0 = *(const float4*)(xr0 + ks * 8);
    float4 xf1 = *(const float4*)(xr1 + ks * 8);
    h2v a0 = __builtin_amdgcn_cvt_pkrtz(xf0.x, xf0.y);
    h2v b0 = __builtin_amdgcn_cvt_pkrtz(xf0.z, xf0.w);
    h4 f0 = __builtin_shufflevector(a0, b0, 0, 1, 2, 3);
    h2v a1 = __builtin_amdgcn_cvt_pkrtz(xf1.x, xf1.y);
    h2v b1 = __builtin_amdgcn_cvt_pkrtz(xf1.z, xf1.w);
    h4 f1 = __builtin_shufflevector(a1, b1, 0, 1, 2, 3);
    h4 wk = bch4(*(const uint2*)&wLds[(32 + l31)*66 + ks*4 + 2*hi]);
    h4 wv = bch4(*(const uint2*)&wLds[(64 + l31)*66 + ks*4 + 2*hi]);
    h4 wq = bch4(*(const uint2*)&wLds[l31*66 + ks*4 + 2*hi]);
    ak0 = mfma8(f0, wk, ak0);          // k: lane=hd-col, regs=node-rows
    ak1 = mfma8(f1, wk, ak1);
    av0 = mfma8(f0, wv, av0);
    av1 = mfma8(f1, wv, av1);
    aq  = mfma8(wq, half ? f1 : f0, aq);   // q^T of own tile: lane=node, regs=hd
  }
  __syncthreads();                     // all waves done READING wLds -> overlay OK

  #pragma unroll
  for (int r = 0; r < 16; ++r) {
    int rc = (r & 3) + 8*(r >> 2) + 4*hi;
    int n0 = w*32 + rc, n1 = n0 + 128;
    kS[n0 * 36 + l31] = (__fp16)ak0[r];
    kS[n1 * 36 + l31] = (__fp16)ak1[r];
    vt32[l31 * 260 + n0] = (__fp16)av0[r];
    vt32[l31 * 260 + n1] = (__fp16)av1[r];
  }
  // Q B-frags straight from aq regs
  h4 Qf[4];
  #pragma unroll
  for (int h = 0; h < 4; ++h) {
    h2v qa = __builtin_amdgcn_cvt_pkrtz(aq[4*h],     aq[4*h + 1]);
    h2v qb = __builtin_amdgcn_cvt_pkrtz(aq[4*h + 2], aq[4*h + 3]);
    Qf[h] = __builtin_shufflevector(qa, qb, 0, 1, 2, 3);
  }
  __syncthreads();                     // kS/vt32 ready

  // ---- attention: 2 head-pair passes (live regs < 128 -> no spill) ----
  const float sc2 = 0.51006977f;       // (1/sqrt(8)) * log2(e)
  const h2v one2 = bch2(0x3C003C00u);  // (1.0h, 1.0h)
  #pragma unroll
  for (int hp = 0; hp < 2; ++hp) {
    int h0 = 2*hp, h1 = 2*hp + 1;
    f32x16 accO0 = fzero(), accO1 = fzero();
    float lp0 = 0.f, lp1 = 0.f;
    #pragma unroll
    for (int kt = 0; kt < 8; ++kt) {
      u32 mwh = mw8[kt];
      float mbv[16];
      #pragma unroll
      for (int r = 0; r < 16; ++r) {   // select on constants, shared across pair
        int bp = (r & 3) + 8*(r >> 2);
        mbv[r] = ((mwh >> bp) & 1u) ? -8.0f : -1e30f;
      }
      u32 pw0[8], pw1[8];
      {
        h4 Kf = bch4(*(const uint2*)&kS[(kt*32 + l31)*36 + 8*h0 + 4*hi]);
        f32x16 T = mfma8(Kf, Qf[h0], fzero());   // T[kr][q=l31]
        #pragma unroll
        for (int j = 0; j < 8; ++j) {
          float p0 = __builtin_amdgcn_exp2f(__builtin_fmaf(T[2*j],   sc2, mbv[2*j]));
          float p1 = __builtin_amdgcn_exp2f(__builtin_fmaf(T[2*j+1], sc2, mbv[2*j+1]));
          pw0[j] = bcu(__builtin_amdgcn_cvt_pkrtz(p0, p1));
          lp0 = dot2(bch2(pw0[j]), one2, lp0);
        }
      }
      {
        h4 Kf = bch4(*(const uint2*)&kS[(kt*32 + l31)*36 + 8*h1 + 4*hi]);
        f32x16 T = mfma8(Kf, Qf[h1], fzero());
        #pragma unroll
        for (int j = 0; j < 8; ++j) {
          float p0 = __builtin_amdgcn_exp2f(__builtin_fmaf(T[2*j],   sc2, mbv[2*j]));
          float p1 = __builtin_amdgcn_exp2f(__builtin_fmaf(T[2*j+1], sc2, mbv[2*j+1]));
          pw1[j] = bcu(__builtin_amdgcn_cvt_pkrtz(p0, p1));
          lp1 = dot2(bch2(pw1[j]), one2, lp1);
        }
      }
      __builtin_amdgcn_s_setprio(1);
      #pragma unroll
      for (int kk = 0; kk < 4; ++kk) {
        h4 va = bch4(*(const uint2*)&vt32[l31*260 + kt*32 + kk*8 + 4*hi]);
        accO0 = mfma8(va, bch4(make_uint2(pw0[2*kk], pw0[2*kk+1])), accO0);
        accO1 = mfma8(va, bch4(make_uint2(pw1[2*kk], pw1[2*kk+1])), accO1);
      }
      __builtin_amdgcn_s_setprio(0);
    }
    float lq0 = lp0 + __shfl_xor(lp0, 32);
    float lq1 = lp1 + __shfl_xor(lp1, 32);
    float inv0 = 1.0f / lq0, inv1 = 1.0f / lq1;
    h2v a0 = __builtin_amdgcn_cvt_pkrtz(accO0[4*h0]*inv0,   accO0[4*h0+1]*inv0);
    h2v a1 = __builtin_amdgcn_cvt_pkrtz(accO0[4*h0+2]*inv0, accO0[4*h0+3]*inv0);
    *(uint2*)&oS[(w*32 + l31)*36 + 8*h0 + 4*hi] = make_uint2(bcu(a0), bcu(a1));
    h2v c0 = __builtin_amdgcn_cvt_pkrtz(accO1[4*h1]*inv1,   accO1[4*h1+1]*inv1);
    h2v c1 = __builtin_amdgcn_cvt_pkrtz(accO1[4*h1+2]*inv1, accO1[4*h1+3]*inv1);
    *(uint2*)&oS[(w*32 + l31)*36 + 8*h1 + 4*hi] = make_uint2(bcu(c0), bcu(c1));
  }
  __syncthreads();

  // ---- proj: 2 threads per row; out = oS @ Wo + bo ----
  int pr = t >> 1, d4 = (t & 1) * 4;
  float r4[4] = { boS[d4], boS[d4+1], boS[d4+2], boS[d4+3] };
  #pragma unroll
  for (int p = 0; p < 16; ++p) {
    h2v o2 = bch2(*(const u32*)&oS[pr*36 + 2*p]);
    #pragma unroll
    for (int d = 0; d < 4; ++d)
      r4[d] = dot2(o2, bch2(woS[(d4 + d)*16 + p]), r4[d]);
  }
  float4 o = { r4[0], r4[1], r4[2], r4[3] };
  *(float4*)(out + ((size_t)b * NNODE + half*128 + pr) * DD + d4) = o;
}

extern "C" void kernel_launch(void* const* d_in, const int* in_sizes, int n_in,
                              void* d_out, int out_size, void* d_ws, size_t ws_size,
                              hipStream_t stream)
{
  const float* x  = (const float*)d_in[0];
  const int*   ei = (const int*)d_in[1];
  const float* Wq = (const float*)d_in[2];
  const float* bq = (const float*)d_in[3];
  const float* Wk = (const float*)d_in[4];
  const float* bk = (const float*)d_in[5];
  const float* Wv = (const float*)d_in[6];
  const float* bv = (const float*)d_in[7];
  const float* Wo = (const float*)d_in[8];
  const float* bo = (const float*)d_in[9];
  int E = in_sizes[1] / 2;

  char* ws = (char*)d_ws;
  u32*   mask = (u32*)(ws + 0);                 // 8 KB
  u32*   WtH  = (u32*)(ws + 8192);              // 24 KB: W^T[c][kp] f16-packed
  float* bias = (float*)(ws + 32768);           // 384 B
  u32*   woT2 = (u32*)(ws + 33280);             // 512 B

  hipMemsetAsync(mask, 0, NNODE * 8 * sizeof(u32), stream);
  int prep_work = (96*64 > E) ? 96*64 : E;
  prep_kernel<<<(prep_work + 255)/256, 256, 0, stream>>>(
      Wq, bq, Wk, bk, Wv, bv, Wo, ei, E, mask, WtH, bias, woT2);
  fused_kernel<<<NB * 2, 256, 0, stream>>>(x, WtH, bias, mask, woT2, bo,
                                           (float*)d_out);
}

// Round 20
// 39.498 us; speedup vs baseline: 1.2546x; 1.2368x over previous
//
#include <hip/hip_runtime.h>

typedef unsigned int u32;
typedef __fp16 h2v __attribute__((ext_vector_type(2)));
typedef __fp16 h4 __attribute__((ext_vector_type(4)));
typedef float f32x16 __attribute__((ext_vector_type(16)));

#define NB 256
#define NNODE 256
#define FF 128
#define DD 8
#define HDIM 32

__device__ __forceinline__ float dot2(h2v a, h2v b, float c) {
  return __builtin_amdgcn_fdot2(a, b, c, false);
}
__device__ __forceinline__ h2v bch2(u32 u) { return __builtin_bit_cast(h2v, u); }
__device__ __forceinline__ h4 bch4(uint2 u) { return __builtin_bit_cast(h4, u); }
__device__ __forceinline__ u32 bcu(h2v v) { return __builtin_bit_cast(u32, v); }
__device__ __forceinline__ f32x16 fzero() {
  f32x16 z;
  #pragma unroll
  for (int r = 0; r < 16; ++r) z[r] = 0.f;
  return z;
}
__device__ __forceinline__ f32x16 mfma8(h4 a, h4 b, f32x16 c) {
  return __builtin_amdgcn_mfma_f32_32x32x8f16(a, b, c, 0, 0, 0);
}

// -------- prep: W pack + bias + woT2 + edge scatter (mask pre-zeroed) ----------
__global__ __launch_bounds__(256) void prep_kernel(
    const float* __restrict__ Wq, const float* __restrict__ bq,
    const float* __restrict__ Wk, const float* __restrict__ bk,
    const float* __restrict__ Wv, const float* __restrict__ bv,
    const float* __restrict__ Wo, const int* __restrict__ eidx, int E,
    u32* __restrict__ mask, u32* __restrict__ WtH, float* __restrict__ bias,
    u32* __restrict__ woT2)
{
  int g = blockIdx.x * 256 + threadIdx.x;
  if (g < 96 * 64) {                 // WtH[c][kp]: pack W[2kp][c], W[2kp+1][c]
    int c = g >> 6, f = (g & 63) * 2;
    const float* W = (c < 32) ? Wq : ((c < 64) ? Wk : Wv);
    int cc = c & 31;
    WtH[g] = bcu(__builtin_amdgcn_cvt_pkrtz(W[f*HDIM + cc], W[(f+1)*HDIM + cc]));
  }
  if (g < 96) {
    const float* bb = (g < 32) ? bq : ((g < 64) ? bk : bv);
    bias[g] = bb[g & 31];
  }
  if (g < 128) {                     // woT2[d][p] = pack Wo[2p][d], Wo[2p+1][d]
    int d = g >> 4, p = g & 15;
    woT2[g] = bcu(__builtin_amdgcn_cvt_pkrtz(Wo[(2*p)*DD + d], Wo[(2*p+1)*DD + d]));
  }
  if (g < E) {
    int r = eidx[g], c = eidx[E + g];
    atomicOr(&mask[r*8 + (c >> 5)], 1u << (c & 31));
  }
}

// -------- fused: 2 blocks/batch (4 waves); XCD-paired halves; QKV prefetch -----
__global__ __launch_bounds__(256, 2) void fused_kernel(
    const float* __restrict__ x, const u32* __restrict__ WtH,
    const float* __restrict__ bias, const u32* __restrict__ mask,
    const u32* __restrict__ woT2, const float* __restrict__ bo,
    float* __restrict__ out)
{
  __shared__ u32 wLds[96 * 66];        // 25.3 KB; stride 66 -> banks spread
  __shared__ __fp16 kS[NNODE * 36];    // 18 KB, stride 36 f16
  __shared__ __fp16 vt32[32 * 260];    // 16.3 KB, V^T all heads, stride 260
  __shared__ __fp16 oS[128 * 36];      // 9 KB, own q-rows
  __shared__ u32 woS[128];
  __shared__ float boS[8];

  int t = threadIdx.x, lane = t & 63, w = t >> 6;   // 4 waves
  int l31 = lane & 31, hi = lane >> 5;
  // XCD pairing: halves of batch b are bids b and b+256 -> same XCD (b%8)
  int b = blockIdx.x & 255, half = blockIdx.x >> 8;

  // stage W (coalesced global read, strided LDS write)
  for (int g = t; g < 96 * 64; g += 256)
    wLds[(g >> 6) * 66 + (g & 63)] = WtH[g];
  if (t < 128) woS[t] = woT2[t];
  if (t < 8) boS[t] = bo[t];

  // accumulator init
  f32x16 aq, ak0, av0, ak1, av1;
  #pragma unroll
  for (int r = 0; r < 16; ++r) aq[r] = bias[(r & 3) + 8*(r >> 2) + 4*hi];
  {
    float bk_ = bias[32 + l31], bv_ = bias[64 + l31];
    #pragma unroll
    for (int r = 0; r < 16; ++r) { ak0[r]=bk_; av0[r]=bv_; ak1[r]=bk_; av1[r]=bv_; }
  }

  // adjacency words for own q-row (issued early; overlaps W-stage latency)
  int node = half*128 + w*32 + l31;
  uint4 m0 = *(const uint4*)(mask + node * 8);
  uint4 m1 = *(const uint4*)(mask + node * 8 + 4);
  u32 mw8[8] = { m0.x, m0.y, m0.z, m0.w, m1.x, m1.y, m1.z, m1.w };
  #pragma unroll
  for (int i = 0; i < 8; ++i) mw8[i] = hi ? (mw8[i] >> 4) : mw8[i];

  __syncthreads();                     // wLds ready

  // ---- QKV: merged dual-tile loop, 1-deep x prefetch ----
  const float* xr0 = x + ((size_t)b * NNODE + w*32 + l31) * FF + 4 * hi;
  const float* xr1 = xr0 + (size_t)128 * FF;
  float4 xc0 = *(const float4*)(xr0);
  float4 xc1 = *(const float4*)(xr1);
  #pragma unroll
  for (int ks = 0; ks < 16; ++ks) {
    float4 xn0, xn1;
    if (ks < 15) {                     // issue next loads before this step's chain
      xn0 = *(const float4*)(xr0 + (ks + 1) * 8);
      xn1 = *(const float4*)(xr1 + (ks + 1) * 8);
    }
    h2v a0 = __builtin_amdgcn_cvt_pkrtz(xc0.x, xc0.y);
    h2v b0 = __builtin_amdgcn_cvt_pkrtz(xc0.z, xc0.w);
    h4 f0 = __builtin_shufflevector(a0, b0, 0, 1, 2, 3);
    h2v a1 = __builtin_amdgcn_cvt_pkrtz(xc1.x, xc1.y);
    h2v b1 = __builtin_amdgcn_cvt_pkrtz(xc1.z, xc1.w);
    h4 f1 = __builtin_shufflevector(a1, b1, 0, 1, 2, 3);
    h4 wk = bch4(*(const uint2*)&wLds[(32 + l31)*66 + ks*4 + 2*hi]);
    h4 wv = bch4(*(const uint2*)&wLds[(64 + l31)*66 + ks*4 + 2*hi]);
    h4 wq = bch4(*(const uint2*)&wLds[l31*66 + ks*4 + 2*hi]);
    ak0 = mfma8(f0, wk, ak0);          // k: lane=hd-col, regs=node-rows
    ak1 = mfma8(f1, wk, ak1);
    av0 = mfma8(f0, wv, av0);
    av1 = mfma8(f1, wv, av1);
    aq  = mfma8(wq, half ? f1 : f0, aq);   // q^T of own tile: lane=node, regs=hd
    xc0 = xn0; xc1 = xn1;
  }
  #pragma unroll
  for (int r = 0; r < 16; ++r) {
    int rc = (r & 3) + 8*(r >> 2) + 4*hi;
    int n0 = w*32 + rc, n1 = n0 + 128;
    kS[n0 * 36 + l31] = (__fp16)ak0[r];
    kS[n1 * 36 + l31] = (__fp16)ak1[r];
    vt32[l31 * 260 + n0] = (__fp16)av0[r];
    vt32[l31 * 260 + n1] = (__fp16)av1[r];
  }
  // Q B-frags straight from aq regs
  h4 Qf[4];
  #pragma unroll
  for (int h = 0; h < 4; ++h) {
    h2v qa = __builtin_amdgcn_cvt_pkrtz(aq[4*h],     aq[4*h + 1]);
    h2v qb = __builtin_amdgcn_cvt_pkrtz(aq[4*h + 2], aq[4*h + 3]);
    Qf[h] = __builtin_shufflevector(qa, qb, 0, 1, 2, 3);
  }
  __syncthreads();

  // ---- attention: 4 head-chains in flight ----
  const float sc2 = 0.51006977f;       // (1/sqrt(8)) * log2(e)
  const h2v one2 = bch2(0x3C003C00u);  // (1.0h, 1.0h)
  f32x16 accO[4] = { fzero(), fzero(), fzero(), fzero() };
  float lp[4] = { 0.f, 0.f, 0.f, 0.f };
  #pragma unroll
  for (int kt = 0; kt < 8; ++kt) {
    u32 mwh = mw8[kt];
    float mbv[16];
    #pragma unroll
    for (int r = 0; r < 16; ++r) {     // select on constants, shared across heads
      int bp = (r & 3) + 8*(r >> 2);
      mbv[r] = ((mwh >> bp) & 1u) ? -8.0f : -1e30f;
    }
    u32 pw[4][8];
    #pragma unroll
    for (int h = 0; h < 4; ++h) {
      h4 Kf = bch4(*(const uint2*)&kS[(kt*32 + l31)*36 + 8*h + 4*hi]);
      f32x16 T = mfma8(Kf, Qf[h], fzero());      // T[kr][q=l31]
      #pragma unroll
      for (int j = 0; j < 8; ++j) {
        float p0 = __builtin_amdgcn_exp2f(__builtin_fmaf(T[2*j],   sc2, mbv[2*j]));
        float p1 = __builtin_amdgcn_exp2f(__builtin_fmaf(T[2*j+1], sc2, mbv[2*j+1]));
        pw[h][j] = bcu(__builtin_amdgcn_cvt_pkrtz(p0, p1));
        lp[h] = dot2(bch2(pw[h][j]), one2, lp[h]);   // l-sum on packed pairs
      }
    }
    __builtin_amdgcn_s_setprio(1);
    #pragma unroll
    for (int kk = 0; kk < 4; ++kk) {
      h4 va = bch4(*(const uint2*)&vt32[l31*260 + kt*32 + kk*8 + 4*hi]);
      #pragma unroll
      for (int h = 0; h < 4; ++h)
        accO[h] = mfma8(va, bch4(make_uint2(pw[h][2*kk], pw[h][2*kk+1])), accO[h]);
    }
    __builtin_amdgcn_s_setprio(0);
  }
  // epilogue: head h output lives in accO[h] regs 4h..4h+3 (col q=l31)
  #pragma unroll
  for (int h = 0; h < 4; ++h) {
    float lq = lp[h] + __shfl_xor(lp[h], 32);
    float inv = 1.0f / lq;
    h2v o0 = __builtin_amdgcn_cvt_pkrtz(accO[h][4*h]*inv,   accO[h][4*h+1]*inv);
    h2v o1 = __builtin_amdgcn_cvt_pkrtz(accO[h][4*h+2]*inv, accO[h][4*h+3]*inv);
    *(uint2*)&oS[(w*32 + l31)*36 + 8*h + 4*hi] = make_uint2(bcu(o0), bcu(o1));
  }
  __syncthreads();

  // ---- proj: 2 threads per row; out = oS @ Wo + bo ----
  int pr = t >> 1, d4 = (t & 1) * 4;
  float r4[4] = { boS[d4], boS[d4+1], boS[d4+2], boS[d4+3] };
  #pragma unroll
  for (int p = 0; p < 16; ++p) {
    h2v o2 = bch2(*(const u32*)&oS[pr*36 + 2*p]);
    #pragma unroll
    for (int d = 0; d < 4; ++d)
      r4[d] = dot2(o2, bch2(woS[(d4 + d)*16 + p]), r4[d]);
  }
  float4 o = { r4[0], r4[1], r4[2], r4[3] };
  *(float4*)(out + ((size_t)b * NNODE + half*128 + pr) * DD + d4) = o;
}

extern "C" void kernel_launch(void* const* d_in, const int* in_sizes, int n_in,
                              void* d_out, int out_size, void* d_ws, size_t ws_size,
                              hipStream_t stream)
{
  const float* x  = (const float*)d_in[0];
  const int*   ei = (const int*)d_in[1];
  const float* Wq = (const float*)d_in[2];
  const float* bq = (const float*)d_in[3];
  const float* Wk = (const float*)d_in[4];
  const float* bk = (const float*)d_in[5];
  const float* Wv = (const float*)d_in[6];
  const float* bv = (const float*)d_in[7];
  const float* Wo = (const float*)d_in[8];
  const float* bo = (const float*)d_in[9];
  int E = in_sizes[1] / 2;

  char* ws = (char*)d_ws;
  u32*   mask = (u32*)(ws + 0);                 // 8 KB
  u32*   WtH  = (u32*)(ws + 8192);              // 24 KB: W^T[c][kp] f16-packed
  float* bias = (float*)(ws + 32768);           // 384 B
  u32*   woT2 = (u32*)(ws + 33280);             // 512 B

  hipMemsetAsync(mask, 0, NNODE * 8 * sizeof(u32), stream);
  int prep_work = (96*64 > E) ? 96*64 : E;
  prep_kernel<<<(prep_work + 255)/256, 256, 0, stream>>>(
      Wq, bq, Wk, bk, Wv, bv, Wo, ei, E, mask, WtH, bias, woT2);
  fused_kernel<<<NB * 2, 256, 0, stream>>>(x, WtH, bias, mask, woT2, bo,
                                           (float*)d_out);
}

// Round 21
// 38.280 us; speedup vs baseline: 1.2945x; 1.0318x over previous
//
#include <hip/hip_runtime.h>

typedef unsigned int u32;
typedef __fp16 h2v __attribute__((ext_vector_type(2)));
typedef __fp16 h4 __attribute__((ext_vector_type(4)));
typedef __fp16 h8 __attribute__((ext_vector_type(8)));
typedef float f32x16 __attribute__((ext_vector_type(16)));

#define NB 256
#define NNODE 256
#define FF 128
#define DD 8
#define HDIM 32

__device__ __forceinline__ float dot2(h2v a, h2v b, float c) {
  return __builtin_amdgcn_fdot2(a, b, c, false);
}
__device__ __forceinline__ h2v bch2(u32 u) { return __builtin_bit_cast(h2v, u); }
__device__ __forceinline__ h4 bch4(uint2 u) { return __builtin_bit_cast(h4, u); }
__device__ __forceinline__ h8 bch8(uint4 u) { return __builtin_bit_cast(h8, u); }
__device__ __forceinline__ u32 bcu(h2v v) { return __builtin_bit_cast(u32, v); }
__device__ __forceinline__ f32x16 fzero() {
  f32x16 z;
  #pragma unroll
  for (int r = 0; r < 16; ++r) z[r] = 0.f;
  return z;
}
__device__ __forceinline__ f32x16 mfma8(h4 a, h4 b, f32x16 c) {
  return __builtin_amdgcn_mfma_f32_32x32x8f16(a, b, c, 0, 0, 0);
}
__device__ __forceinline__ f32x16 mfma16(h8 a, h8 b, f32x16 c) {
  return __builtin_amdgcn_mfma_f32_32x32x16_f16(a, b, c, 0, 0, 0);
}

// -------- prep: W pack + bias + woT2 + edge scatter (mask pre-zeroed) ----------
__global__ __launch_bounds__(256) void prep_kernel(
    const float* __restrict__ Wq, const float* __restrict__ bq,
    const float* __restrict__ Wk, const float* __restrict__ bk,
    const float* __restrict__ Wv, const float* __restrict__ bv,
    const float* __restrict__ Wo, const int* __restrict__ eidx, int E,
    u32* __restrict__ mask, u32* __restrict__ WtH, float* __restrict__ bias,
    u32* __restrict__ woT2)
{
  int g = blockIdx.x * 256 + threadIdx.x;
  if (g < 96 * 64) {                 // WtH[c][kp]: pack W[2kp][c], W[2kp+1][c]
    int c = g >> 6, f = (g & 63) * 2;
    const float* W = (c < 32) ? Wq : ((c < 64) ? Wk : Wv);
    int cc = c & 31;
    WtH[g] = bcu(__builtin_amdgcn_cvt_pkrtz(W[f*HDIM + cc], W[(f+1)*HDIM + cc]));
  }
  if (g < 96) {
    const float* bb = (g < 32) ? bq : ((g < 64) ? bk : bv);
    bias[g] = bb[g & 31];
  }
  if (g < 128) {                     // woT2[d][p] = pack Wo[2p][d], Wo[2p+1][d]
    int d = g >> 4, p = g & 15;
    woT2[g] = bcu(__builtin_amdgcn_cvt_pkrtz(Wo[(2*p)*DD + d], Wo[(2*p+1)*DD + d]));
  }
  if (g < E) {
    int r = eidx[g], c = eidx[E + g];
    atomicOr(&mask[r*8 + (c >> 5)], 1u << (c & 31));
  }
}

// -------- fused: 2 blocks/batch (XCD-paired); K=16 MFMAs for QKV and PV --------
__global__ __launch_bounds__(256, 2) void fused_kernel(
    const float* __restrict__ x, const u32* __restrict__ WtH,
    const float* __restrict__ bias, const u32* __restrict__ mask,
    const u32* __restrict__ woT2, const float* __restrict__ bo,
    float* __restrict__ out)
{
  __shared__ u32 wLds[96 * 68];        // 26.1 KB; stride 68 u32: 16B-aligned rows,
                                       // b128 reads hit 8 distinct bank-quads
  __shared__ __fp16 kS[NNODE * 36];    // 18 KB
  __shared__ __fp16 vt32[32 * 264];    // 16.9 KB; stride 264 f16 (528B, 16B-aligned)
  __shared__ u32 woS[128];
  __shared__ float boS[8];
  __fp16* oS = (__fp16*)wLds;          // 9 KB alias; wLds dead after QKV phase

  int t = threadIdx.x, lane = t & 63, w = t >> 6;   // 4 waves
  int l31 = lane & 31, hi = lane >> 5;
  // XCD pairing: halves of batch b are bids b and b+256 -> same XCD (b%8)
  int b = blockIdx.x & 255, half = blockIdx.x >> 8;

  for (int g = t; g < 96 * 64; g += 256)
    wLds[(g >> 6) * 68 + (g & 63)] = WtH[g];
  if (t < 128) woS[t] = woT2[t];
  if (t < 8) boS[t] = bo[t];

  // accumulator init
  f32x16 aq, ak0, av0, ak1, av1;
  #pragma unroll
  for (int r = 0; r < 16; ++r) aq[r] = bias[(r & 3) + 8*(r >> 2) + 4*hi];
  {
    float bk_ = bias[32 + l31], bv_ = bias[64 + l31];
    #pragma unroll
    for (int r = 0; r < 16; ++r) { ak0[r]=bk_; av0[r]=bv_; ak1[r]=bk_; av1[r]=bv_; }
  }

  // adjacency words for own q-row
  int node = half*128 + w*32 + l31;
  uint4 m0 = *(const uint4*)(mask + node * 8);
  uint4 m1 = *(const uint4*)(mask + node * 8 + 4);
  u32 mw8[8] = { m0.x, m0.y, m0.z, m0.w, m1.x, m1.y, m1.z, m1.w };
  #pragma unroll
  for (int i = 0; i < 8; ++i) mw8[i] = hi ? (mw8[i] >> 4) : mw8[i];

  __syncthreads();                     // wLds ready

  // ---- QKV: K=16 mfma, 8 steps, dual tile, 1-deep x prefetch ----
  // A/B frag (K=16): k = 8*hi + j, j=0..7 -> 8 contiguous f16 / 8 floats of x
  const float* xr0 = x + ((size_t)b * NNODE + w*32 + l31) * FF + 8 * hi;
  const float* xr1 = xr0 + (size_t)128 * FF;
  float4 xc0a = *(const float4*)(xr0),     xc0b = *(const float4*)(xr0 + 4);
  float4 xc1a = *(const float4*)(xr1),     xc1b = *(const float4*)(xr1 + 4);
  #pragma unroll
  for (int ks = 0; ks < 8; ++ks) {
    float4 xn0a, xn0b, xn1a, xn1b;
    if (ks < 7) {                      // issue next loads before this step's chain
      xn0a = *(const float4*)(xr0 + (ks + 1) * 16);
      xn0b = *(const float4*)(xr0 + (ks + 1) * 16 + 4);
      xn1a = *(const float4*)(xr1 + (ks + 1) * 16);
      xn1b = *(const float4*)(xr1 + (ks + 1) * 16 + 4);
    }
    h8 f0 = bch8(make_uint4(bcu(__builtin_amdgcn_cvt_pkrtz(xc0a.x, xc0a.y)),
                            bcu(__builtin_amdgcn_cvt_pkrtz(xc0a.z, xc0a.w)),
                            bcu(__builtin_amdgcn_cvt_pkrtz(xc0b.x, xc0b.y)),
                            bcu(__builtin_amdgcn_cvt_pkrtz(xc0b.z, xc0b.w))));
    h8 f1 = bch8(make_uint4(bcu(__builtin_amdgcn_cvt_pkrtz(xc1a.x, xc1a.y)),
                            bcu(__builtin_amdgcn_cvt_pkrtz(xc1a.z, xc1a.w)),
                            bcu(__builtin_amdgcn_cvt_pkrtz(xc1b.x, xc1b.y)),
                            bcu(__builtin_amdgcn_cvt_pkrtz(xc1b.z, xc1b.w))));
    h8 wk = bch8(*(const uint4*)&wLds[(32 + l31)*68 + ks*8 + 4*hi]);
    h8 wv = bch8(*(const uint4*)&wLds[(64 + l31)*68 + ks*8 + 4*hi]);
    h8 wq = bch8(*(const uint4*)&wLds[l31*68 + ks*8 + 4*hi]);
    ak0 = mfma16(f0, wk, ak0);         // k: lane=hd-col, regs=node-rows
    ak1 = mfma16(f1, wk, ak1);
    av0 = mfma16(f0, wv, av0);
    av1 = mfma16(f1, wv, av1);
    aq  = mfma16(wq, half ? f1 : f0, aq);  // q^T of own tile: lane=node, regs=hd
    xc0a = xn0a; xc0b = xn0b; xc1a = xn1a; xc1b = xn1b;
  }
  #pragma unroll
  for (int r = 0; r < 16; ++r) {
    int rc = (r & 3) + 8*(r >> 2) + 4*hi;
    int n0 = w*32 + rc, n1 = n0 + 128;
    kS[n0 * 36 + l31] = (__fp16)ak0[r];
    kS[n1 * 36 + l31] = (__fp16)ak1[r];
    vt32[l31 * 264 + n0] = (__fp16)av0[r];
    vt32[l31 * 264 + n1] = (__fp16)av1[r];
  }
  // Q B-frags for K=8 QK^T straight from aq regs
  h4 Qf[4];
  #pragma unroll
  for (int h = 0; h < 4; ++h) {
    h2v qa = __builtin_amdgcn_cvt_pkrtz(aq[4*h],     aq[4*h + 1]);
    h2v qb = __builtin_amdgcn_cvt_pkrtz(aq[4*h + 2], aq[4*h + 3]);
    Qf[h] = __builtin_shufflevector(qa, qb, 0, 1, 2, 3);
  }
  __syncthreads();                     // kS/vt32 ready (wLds now dead -> oS alias)

  // ---- attention: QK^T K=8; PV K=16 via permlane32_swap B-frag build ----
  const float sc2 = 0.51006977f;       // (1/sqrt(8)) * log2(e)
  const h2v one2 = bch2(0x3C003C00u);  // (1.0h, 1.0h)
  f32x16 accO[4] = { fzero(), fzero(), fzero(), fzero() };
  float lp[4] = { 0.f, 0.f, 0.f, 0.f };
  #pragma unroll
  for (int kt = 0; kt < 8; ++kt) {
    u32 mwh = mw8[kt];
    float mbv[16];
    #pragma unroll
    for (int r = 0; r < 16; ++r) {     // select on constants, shared across heads
      int bp = (r & 3) + 8*(r >> 2);
      mbv[r] = ((mwh >> bp) & 1u) ? -8.0f : -1e30f;
    }
    u32 pw[4][8];
    #pragma unroll
    for (int h = 0; h < 4; ++h) {
      h4 Kf = bch4(*(const uint2*)&kS[(kt*32 + l31)*36 + 8*h + 4*hi]);
      f32x16 T = mfma8(Kf, Qf[h], fzero());      // T[kr][q=l31]
      #pragma unroll
      for (int j = 0; j < 8; ++j) {
        float p0 = __builtin_amdgcn_exp2f(__builtin_fmaf(T[2*j],   sc2, mbv[2*j]));
        float p1 = __builtin_amdgcn_exp2f(__builtin_fmaf(T[2*j+1], sc2, mbv[2*j+1]));
        pw[h][j] = bcu(__builtin_amdgcn_cvt_pkrtz(p0, p1));
        lp[h] = dot2(bch2(pw[h][j]), one2, lp[h]);   // l-sum on packed pairs
      }
    }
    // V^T A-frags (K=16): row=hd, k = kk16*16 + 8hi + j -> b128, shared by heads
    h8 va0 = bch8(*(const uint4*)&vt32[l31*264 + kt*32 + 8*hi]);
    h8 va1 = bch8(*(const uint4*)&vt32[l31*264 + kt*32 + 16 + 8*hi]);
    __builtin_amdgcn_s_setprio(1);
    #pragma unroll
    for (int h = 0; h < 4; ++h) {
      // B-frag build: T C-frag gives kr {4hi+0..3, 8+4hi+0..3} per word-quad;
      // K=16 B needs k = 8hi+0..7. {B0,B2}=swap(w0,w2), {B1,B3}=swap(w1,w3).
      u32 a0 = pw[h][0], a1 = pw[h][1], a2 = pw[h][2], a3 = pw[h][3];
      asm("v_permlane32_swap_b32 %0, %1" : "+v"(a0), "+v"(a2));
      asm("v_permlane32_swap_b32 %0, %1" : "+v"(a1), "+v"(a3));
      accO[h] = mfma16(va0, bch8(make_uint4(a0, a1, a2, a3)), accO[h]);
      u32 c0 = pw[h][4], c1 = pw[h][5], c2 = pw[h][6], c3 = pw[h][7];
      asm("v_permlane32_swap_b32 %0, %1" : "+v"(c0), "+v"(c2));
      asm("v_permlane32_swap_b32 %0, %1" : "+v"(c1), "+v"(c3));
      accO[h] = mfma16(va1, bch8(make_uint4(c0, c1, c2, c3)), accO[h]);
    }
    __builtin_amdgcn_s_setprio(0);
  }
  // epilogue: head h output lives in accO[h] regs 4h..4h+3 (col q=l31)
  #pragma unroll
  for (int h = 0; h < 4; ++h) {
    float lq = lp[h] + __shfl_xor(lp[h], 32);
    float inv = 1.0f / lq;
    h2v o0 = __builtin_amdgcn_cvt_pkrtz(accO[h][4*h]*inv,   accO[h][4*h+1]*inv);
    h2v o1 = __builtin_amdgcn_cvt_pkrtz(accO[h][4*h+2]*inv, accO[h][4*h+3]*inv);
    *(uint2*)&oS[(w*32 + l31)*36 + 8*h + 4*hi] = make_uint2(bcu(o0), bcu(o1));
  }
  __syncthreads();

  // ---- proj: 2 threads per row; out = oS @ Wo + bo ----
  int pr = t >> 1, d4 = (t & 1) * 4;
  float r4[4] = { boS[d4], boS[d4+1], boS[d4+2], boS[d4+3] };
  #pragma unroll
  for (int p = 0; p < 16; ++p) {
    h2v o2 = bch2(*(const u32*)&oS[pr*36 + 2*p]);
    #pragma unroll
    for (int d = 0; d < 4; ++d)
      r4[d] = dot2(o2, bch2(woS[(d4 + d)*16 + p]), r4[d]);
  }
  float4 o = { r4[0], r4[1], r4[2], r4[3] };
  *(float4*)(out + ((size_t)b * NNODE + half*128 + pr) * DD + d4) = o;
}

extern "C" void kernel_launch(void* const* d_in, const int* in_sizes, int n_in,
                              void* d_out, int out_size, void* d_ws, size_t ws_size,
                              hipStream_t stream)
{
  const float* x  = (const float*)d_in[0];
  const int*   ei = (const int*)d_in[1];
  const float* Wq = (const float*)d_in[2];
  const float* bq = (const float*)d_in[3];
  const float* Wk = (const float*)d_in[4];
  const float* bk = (const float*)d_in[5];
  const float* Wv = (const float*)d_in[6];
  const float* bv = (const float*)d_in[7];
  const float* Wo = (const float*)d_in[8];
  const float* bo = (const float*)d_in[9];
  int E = in_sizes[1] / 2;

  char* ws = (char*)d_ws;
  u32*   mask = (u32*)(ws + 0);                 // 8 KB
  u32*   WtH  = (u32*)(ws + 8192);              // 24 KB: W^T[c][kp] f16-packed
  float* bias = (float*)(ws + 32768);           // 384 B
  u32*   woT2 = (u32*)(ws + 33280);             // 512 B

  hipMemsetAsync(mask, 0, NNODE * 8 * sizeof(u32), stream);
  int prep_work = (96*64 > E) ? 96*64 : E;
  prep_kernel<<<(prep_work + 255)/256, 256, 0, stream>>>(
      Wq, bq, Wk, bk, Wv, bv, Wo, ei, E, mask, WtH, bias, woT2);
  fused_kernel<<<NB * 2, 256, 0, stream>>>(x, WtH, bias, mask, woT2, bo,
                                           (float*)d_out);
}

// Round 22
// 35.988 us; speedup vs baseline: 1.3769x; 1.0637x over previous
//
#include <hip/hip_runtime.h>

typedef unsigned int u32;
typedef __fp16 h2v __attribute__((ext_vector_type(2)));
typedef __fp16 h4 __attribute__((ext_vector_type(4)));
typedef __fp16 h8 __attribute__((ext_vector_type(8)));
typedef float f32x16 __attribute__((ext_vector_type(16)));

#define NB 256
#define NNODE 256
#define FF 128
#define DD 8
#define HDIM 32

__device__ __forceinline__ float dot2(h2v a, h2v b, float c) {
  return __builtin_amdgcn_fdot2(a, b, c, false);
}
__device__ __forceinline__ h2v bch2(u32 u) { return __builtin_bit_cast(h2v, u); }
__device__ __forceinline__ h4 bch4(uint2 u) { return __builtin_bit_cast(h4, u); }
__device__ __forceinline__ h8 bch8(uint4 u) { return __builtin_bit_cast(h8, u); }
__device__ __forceinline__ u32 bcu(h2v v) { return __builtin_bit_cast(u32, v); }
__device__ __forceinline__ f32x16 fzero() {
  f32x16 z;
  #pragma unroll
  for (int r = 0; r < 16; ++r) z[r] = 0.f;
  return z;
}
__device__ __forceinline__ f32x16 mfma8(h4 a, h4 b, f32x16 c) {
  return __builtin_amdgcn_mfma_f32_32x32x8f16(a, b, c, 0, 0, 0);
}
__device__ __forceinline__ f32x16 mfma16(h8 a, h8 b, f32x16 c) {
  return __builtin_amdgcn_mfma_f32_32x32x16_f16(a, b, c, 0, 0, 0);
}

// -------- prep: W pack + bias + woT2 + edge scatter (mask pre-zeroed) ----------
__global__ __launch_bounds__(256) void prep_kernel(
    const float* __restrict__ Wq, const float* __restrict__ bq,
    const float* __restrict__ Wk, const float* __restrict__ bk,
    const float* __restrict__ Wv, const float* __restrict__ bv,
    const float* __restrict__ Wo, const int* __restrict__ eidx, int E,
    u32* __restrict__ mask, u32* __restrict__ WtH, float* __restrict__ bias,
    u32* __restrict__ woT2)
{
  int g = blockIdx.x * 256 + threadIdx.x;
  if (g < 96 * 64) {                 // WtH[c][kp]: pack W[2kp][c], W[2kp+1][c]
    int c = g >> 6, f = (g & 63) * 2;
    const float* W = (c < 32) ? Wq : ((c < 64) ? Wk : Wv);
    int cc = c & 31;
    WtH[g] = bcu(__builtin_amdgcn_cvt_pkrtz(W[f*HDIM + cc], W[(f+1)*HDIM + cc]));
  }
  if (g < 96) {
    const float* bb = (g < 32) ? bq : ((g < 64) ? bk : bv);
    bias[g] = bb[g & 31];
  }
  if (g < 128) {                     // woT2[d][p] = pack Wo[2p][d], Wo[2p+1][d]
    int d = g >> 4, p = g & 15;
    woT2[g] = bcu(__builtin_amdgcn_cvt_pkrtz(Wo[(2*p)*DD + d], Wo[(2*p+1)*DD + d]));
  }
  if (g < E) {
    int r = eidx[g], c = eidx[E + g];
    atomicOr(&mask[r*8 + (c >> 5)], 1u << (c & 31));
  }
}

// -------- fused: 2 blocks/batch (XCD-paired); K=16 QKV/PV; mask-as-C QK^T ------
__global__ __launch_bounds__(256, 2) void fused_kernel(
    const float* __restrict__ x, const u32* __restrict__ WtH,
    const float* __restrict__ bias, const u32* __restrict__ mask,
    const u32* __restrict__ woT2, const float* __restrict__ bo,
    float* __restrict__ out)
{
  __shared__ u32 wLds[96 * 68];        // 26.1 KB; stride 68 u32 (16B-aligned rows)
  __shared__ __fp16 kS[NNODE * 36];    // 18 KB
  __shared__ __fp16 vt32[32 * 264];    // 16.9 KB; stride 264 f16 (528B)
  __shared__ u32 woS[128];
  __shared__ float boS[8];
  __fp16* oS = (__fp16*)wLds;          // 9 KB alias; wLds dead after QKV phase

  int t = threadIdx.x, lane = t & 63, w = t >> 6;   // 4 waves
  int l31 = lane & 31, hi = lane >> 5;
  // XCD pairing: halves of batch b are bids b and b+256 -> same XCD (b%8)
  int b = blockIdx.x & 255, half = blockIdx.x >> 8;

  for (int g = t; g < 96 * 64; g += 256)
    wLds[(g >> 6) * 68 + (g & 63)] = WtH[g];
  if (t < 128) woS[t] = woT2[t];
  if (t < 8) boS[t] = bo[t];

  // accumulator init
  f32x16 aq, ak0, av0, ak1, av1;
  #pragma unroll
  for (int r = 0; r < 16; ++r) aq[r] = bias[(r & 3) + 8*(r >> 2) + 4*hi];
  {
    float bk_ = bias[32 + l31], bv_ = bias[64 + l31];
    #pragma unroll
    for (int r = 0; r < 16; ++r) { ak0[r]=bk_; av0[r]=bv_; ak1[r]=bk_; av1[r]=bv_; }
  }

  // adjacency words for own q-row
  int node = half*128 + w*32 + l31;
  uint4 m0 = *(const uint4*)(mask + node * 8);
  uint4 m1 = *(const uint4*)(mask + node * 8 + 4);
  u32 mw8[8] = { m0.x, m0.y, m0.z, m0.w, m1.x, m1.y, m1.z, m1.w };
  #pragma unroll
  for (int i = 0; i < 8; ++i) mw8[i] = hi ? (mw8[i] >> 4) : mw8[i];

  __syncthreads();                     // wLds ready

  // ---- QKV: K=16 mfma, 8 steps, dual tile, 1-deep x prefetch ----
  const float* xr0 = x + ((size_t)b * NNODE + w*32 + l31) * FF + 8 * hi;
  const float* xr1 = xr0 + (size_t)128 * FF;
  float4 xc0a = *(const float4*)(xr0),     xc0b = *(const float4*)(xr0 + 4);
  float4 xc1a = *(const float4*)(xr1),     xc1b = *(const float4*)(xr1 + 4);
  #pragma unroll
  for (int ks = 0; ks < 8; ++ks) {
    float4 xn0a, xn0b, xn1a, xn1b;
    if (ks < 7) {                      // issue next loads before this step's chain
      xn0a = *(const float4*)(xr0 + (ks + 1) * 16);
      xn0b = *(const float4*)(xr0 + (ks + 1) * 16 + 4);
      xn1a = *(const float4*)(xr1 + (ks + 1) * 16);
      xn1b = *(const float4*)(xr1 + (ks + 1) * 16 + 4);
    }
    h8 f0 = bch8(make_uint4(bcu(__builtin_amdgcn_cvt_pkrtz(xc0a.x, xc0a.y)),
                            bcu(__builtin_amdgcn_cvt_pkrtz(xc0a.z, xc0a.w)),
                            bcu(__builtin_amdgcn_cvt_pkrtz(xc0b.x, xc0b.y)),
                            bcu(__builtin_amdgcn_cvt_pkrtz(xc0b.z, xc0b.w))));
    h8 f1 = bch8(make_uint4(bcu(__builtin_amdgcn_cvt_pkrtz(xc1a.x, xc1a.y)),
                            bcu(__builtin_amdgcn_cvt_pkrtz(xc1a.z, xc1a.w)),
                            bcu(__builtin_amdgcn_cvt_pkrtz(xc1b.x, xc1b.y)),
                            bcu(__builtin_amdgcn_cvt_pkrtz(xc1b.z, xc1b.w))));
    h8 wk = bch8(*(const uint4*)&wLds[(32 + l31)*68 + ks*8 + 4*hi]);
    h8 wv = bch8(*(const uint4*)&wLds[(64 + l31)*68 + ks*8 + 4*hi]);
    h8 wq = bch8(*(const uint4*)&wLds[l31*68 + ks*8 + 4*hi]);
    ak0 = mfma16(f0, wk, ak0);         // k: lane=hd-col, regs=node-rows
    ak1 = mfma16(f1, wk, ak1);
    av0 = mfma16(f0, wv, av0);
    av1 = mfma16(f1, wv, av1);
    aq  = mfma16(wq, half ? f1 : f0, aq);  // q^T of own tile: lane=node, regs=hd
    xc0a = xn0a; xc0b = xn0b; xc1a = xn1a; xc1b = xn1b;
  }
  #pragma unroll
  for (int r = 0; r < 16; ++r) {
    int rc = (r & 3) + 8*(r >> 2) + 4*hi;
    int n0 = w*32 + rc, n1 = n0 + 128;
    kS[n0 * 36 + l31] = (__fp16)ak0[r];
    kS[n1 * 36 + l31] = (__fp16)ak1[r];
    vt32[l31 * 264 + n0] = (__fp16)av0[r];
    vt32[l31 * 264 + n1] = (__fp16)av1[r];
  }
  // Q B-frags for K=8 QK^T, PRE-SCALED by sc2 = (1/sqrt 8)*log2(e):
  // T then arrives in log2 domain; mask/anchor added via mfma C operand.
  const float sc2 = 0.51006977f;
  h4 Qf[4];
  #pragma unroll
  for (int h = 0; h < 4; ++h) {
    h2v qa = __builtin_amdgcn_cvt_pkrtz(aq[4*h]*sc2,     aq[4*h + 1]*sc2);
    h2v qb = __builtin_amdgcn_cvt_pkrtz(aq[4*h + 2]*sc2, aq[4*h + 3]*sc2);
    Qf[h] = __builtin_shufflevector(qa, qb, 0, 1, 2, 3);
  }
  __syncthreads();                     // kS/vt32 ready (wLds now dead -> oS alias)

  // ---- attention: QK^T K=8 with mask-as-C; PV K=16 via permlane32_swap --------
  const h2v one2 = bch2(0x3C003C00u);  // (1.0h, 1.0h)
  f32x16 accO[4] = { fzero(), fzero(), fzero(), fzero() };
  float lp[4] = { 0.f, 0.f, 0.f, 0.f };
  #pragma unroll
  for (int kt = 0; kt < 8; ++kt) {
    u32 mwh = mw8[kt];
    f32x16 mbvV;                       // C operand: anchor -8 or mask -1e30
    #pragma unroll
    for (int r = 0; r < 16; ++r) {
      int bp = (r & 3) + 8*(r >> 2);
      mbvV[r] = ((mwh >> bp) & 1u) ? -8.0f : -1e30f;
    }
    u32 pw[4][8];
    #pragma unroll
    for (int h = 0; h < 4; ++h) {
      h4 Kf = bch4(*(const uint2*)&kS[(kt*32 + l31)*36 + 8*h + 4*hi]);
      f32x16 T = mfma8(Kf, Qf[h], mbvV);   // T[r] = s*sc2 + (-8 | -1e30)
      #pragma unroll
      for (int j = 0; j < 8; ++j) {
        float p0 = __builtin_amdgcn_exp2f(T[2*j]);
        float p1 = __builtin_amdgcn_exp2f(T[2*j+1]);
        pw[h][j] = bcu(__builtin_amdgcn_cvt_pkrtz(p0, p1));
        lp[h] = dot2(bch2(pw[h][j]), one2, lp[h]);   // l-sum on packed pairs
      }
    }
    // V^T A-frags (K=16): row=hd, k = kk16*16 + 8hi + j -> b128, shared by heads
    h8 va0 = bch8(*(const uint4*)&vt32[l31*264 + kt*32 + 8*hi]);
    h8 va1 = bch8(*(const uint4*)&vt32[l31*264 + kt*32 + 16 + 8*hi]);
    __builtin_amdgcn_s_setprio(1);
    #pragma unroll
    for (int h = 0; h < 4; ++h) {
      // B-frag build: {B0,B2}=swap(w0,w2), {B1,B3}=swap(w1,w3)
      u32 a0 = pw[h][0], a1 = pw[h][1], a2 = pw[h][2], a3 = pw[h][3];
      asm("v_permlane32_swap_b32 %0, %1" : "+v"(a0), "+v"(a2));
      asm("v_permlane32_swap_b32 %0, %1" : "+v"(a1), "+v"(a3));
      accO[h] = mfma16(va0, bch8(make_uint4(a0, a1, a2, a3)), accO[h]);
      u32 c0 = pw[h][4], c1 = pw[h][5], c2 = pw[h][6], c3 = pw[h][7];
      asm("v_permlane32_swap_b32 %0, %1" : "+v"(c0), "+v"(c2));
      asm("v_permlane32_swap_b32 %0, %1" : "+v"(c1), "+v"(c3));
      accO[h] = mfma16(va1, bch8(make_uint4(c0, c1, c2, c3)), accO[h]);
    }
    __builtin_amdgcn_s_setprio(0);
  }
  // epilogue: head h output lives in accO[h] regs 4h..4h+3 (col q=l31)
  #pragma unroll
  for (int h = 0; h < 4; ++h) {
    float lq = lp[h] + __shfl_xor(lp[h], 32);
    float inv = 1.0f / lq;
    h2v o0 = __builtin_amdgcn_cvt_pkrtz(accO[h][4*h]*inv,   accO[h][4*h+1]*inv);
    h2v o1 = __builtin_amdgcn_cvt_pkrtz(accO[h][4*h+2]*inv, accO[h][4*h+3]*inv);
    *(uint2*)&oS[(w*32 + l31)*36 + 8*h + 4*hi] = make_uint2(bcu(o0), bcu(o1));
  }
  __syncthreads();

  // ---- proj: 2 threads per row; out = oS @ Wo + bo ----
  int pr = t >> 1, d4 = (t & 1) * 4;
  float r4[4] = { boS[d4], boS[d4+1], boS[d4+2], boS[d4+3] };
  #pragma unroll
  for (int p = 0; p < 16; ++p) {
    h2v o2 = bch2(*(const u32*)&oS[pr*36 + 2*p]);
    #pragma unroll
    for (int d = 0; d < 4; ++d)
      r4[d] = dot2(o2, bch2(woS[(d4 + d)*16 + p]), r4[d]);
  }
  float4 o = { r4[0], r4[1], r4[2], r4[3] };
  *(float4*)(out + ((size_t)b * NNODE + half*128 + pr) * DD + d4) = o;
}

extern "C" void kernel_launch(void* const* d_in, const int* in_sizes, int n_in,
                              void* d_out, int out_size, void* d_ws, size_t ws_size,
                              hipStream_t stream)
{
  const float* x  = (const float*)d_in[0];
  const int*   ei = (const int*)d_in[1];
  const float* Wq = (const float*)d_in[2];
  const float* bq = (const float*)d_in[3];
  const float* Wk = (const float*)d_in[4];
  const float* bk = (const float*)d_in[5];
  const float* Wv = (const float*)d_in[6];
  const float* bv = (const float*)d_in[7];
  const float* Wo = (const float*)d_in[8];
  const float* bo = (const float*)d_in[9];
  int E = in_sizes[1] / 2;

  char* ws = (char*)d_ws;
  u32*   mask = (u32*)(ws + 0);                 // 8 KB
  u32*   WtH  = (u32*)(ws + 8192);              // 24 KB: W^T[c][kp] f16-packed
  float* bias = (float*)(ws + 32768);           // 384 B
  u32*   woT2 = (u32*)(ws + 33280);             // 512 B

  hipMemsetAsync(mask, 0, NNODE * 8 * sizeof(u32), stream);
  int prep_work = (96*64 > E) ? 96*64 : E;
  prep_kernel<<<(prep_work + 255)/256, 256, 0, stream>>>(
      Wq, bq, Wk, bk, Wv, bv, Wo, ei, E, mask, WtH, bias, woT2);
  fused_kernel<<<NB * 2, 256, 0, stream>>>(x, WtH, bias, mask, woT2, bo,
                                           (float*)d_out);
}

// Round 23
// 34.650 us; speedup vs baseline: 1.4301x; 1.0386x over previous
//
#include <hip/hip_runtime.h>

typedef unsigned int u32;
typedef __fp16 h2v __attribute__((ext_vector_type(2)));
typedef __fp16 h4 __attribute__((ext_vector_type(4)));
typedef __fp16 h8 __attribute__((ext_vector_type(8)));
typedef float f32x16 __attribute__((ext_vector_type(16)));

#define NB 256
#define NNODE 256
#define FF 128
#define DD 8
#define HDIM 32

__device__ __forceinline__ float dot2(h2v a, h2v b, float c) {
  return __builtin_amdgcn_fdot2(a, b, c, false);
}
__device__ __forceinline__ h2v bch2(u32 u) { return __builtin_bit_cast(h2v, u); }
__device__ __forceinline__ h4 bch4(uint2 u) { return __builtin_bit_cast(h4, u); }
__device__ __forceinline__ h8 bch8(uint4 u) { return __builtin_bit_cast(h8, u); }
__device__ __forceinline__ u32 bcu(h2v v) { return __builtin_bit_cast(u32, v); }
__device__ __forceinline__ f32x16 fzero() {
  f32x16 z;
  #pragma unroll
  for (int r = 0; r < 16; ++r) z[r] = 0.f;
  return z;
}
__device__ __forceinline__ f32x16 mfma8(h4 a, h4 b, f32x16 c) {
  return __builtin_amdgcn_mfma_f32_32x32x8f16(a, b, c, 0, 0, 0);
}
__device__ __forceinline__ f32x16 mfma16(h8 a, h8 b, f32x16 c) {
  return __builtin_amdgcn_mfma_f32_32x32x16_f16(a, b, c, 0, 0, 0);
}

// -------- prep: W pack + bias + woT2 + edge scatter (mask pre-zeroed) ----------
__global__ __launch_bounds__(256) void prep_kernel(
    const float* __restrict__ Wq, const float* __restrict__ bq,
    const float* __restrict__ Wk, const float* __restrict__ bk,
    const float* __restrict__ Wv, const float* __restrict__ bv,
    const float* __restrict__ Wo, const int* __restrict__ eidx, int E,
    u32* __restrict__ mask, u32* __restrict__ WtH, float* __restrict__ bias,
    u32* __restrict__ woT2)
{
  int g = blockIdx.x * 256 + threadIdx.x;
  if (g < 96 * 64) {                 // WtH[c][kp]: pack W[2kp][c], W[2kp+1][c]
    int c = g >> 6, f = (g & 63) * 2;
    const float* W = (c < 32) ? Wq : ((c < 64) ? Wk : Wv);
    int cc = c & 31;
    WtH[g] = bcu(__builtin_amdgcn_cvt_pkrtz(W[f*HDIM + cc], W[(f+1)*HDIM + cc]));
  }
  if (g < 96) {
    const float* bb = (g < 32) ? bq : ((g < 64) ? bk : bv);
    bias[g] = bb[g & 31];
  }
  if (g < 128) {                     // woT2[d][p] = pack Wo[2p][d], Wo[2p+1][d]
    int d = g >> 4, p = g & 15;
    woT2[g] = bcu(__builtin_amdgcn_cvt_pkrtz(Wo[(2*p)*DD + d], Wo[(2*p+1)*DD + d]));
  }
  if (g < E) {
    int r = eidx[g], c = eidx[E + g];
    atomicOr(&mask[r*8 + (c >> 5)], 1u << (c & 31));
  }
}

// -------- fused: 2 blocks/batch (XCD-paired); K=16 QKV/PV; mask-as-C QK^T ------
__global__ __launch_bounds__(256, 2) void fused_kernel(
    const float* __restrict__ x, const u32* __restrict__ WtH,
    const float* __restrict__ bias, const u32* __restrict__ mask,
    const u32* __restrict__ woT2, const float* __restrict__ bo,
    float* __restrict__ out)
{
  __shared__ u32 wLds[96 * 68];        // 26.1 KB; stride 68 u32 (272B, 16B-aligned)
  __shared__ __fp16 kS[NNODE * 36];    // 18 KB
  __shared__ __fp16 vt32[32 * 264];    // 16.9 KB; stride 264 f16 (528B)
  __shared__ u32 woS[128];
  __shared__ float boS[8];
  __fp16* oS = (__fp16*)wLds;          // 9 KB alias; wLds dead after QKV phase

  int t = threadIdx.x, lane = t & 63, w = t >> 6;   // 4 waves
  int l31 = lane & 31, hi = lane >> 5;
  // XCD pairing: halves of batch b are bids b and b+256 -> same XCD (b%8)
  int b = blockIdx.x & 255, half = blockIdx.x >> 8;

  // ---- issue x ks=0 loads FIRST (independent of LDS; barrier would fence them)
  const float* xr0 = x + ((size_t)b * NNODE + w*32 + l31) * FF + 8 * hi;
  const float* xr1 = xr0 + (size_t)128 * FF;
  float4 xc0a = *(const float4*)(xr0),     xc0b = *(const float4*)(xr0 + 4);
  float4 xc1a = *(const float4*)(xr1),     xc1b = *(const float4*)(xr1 + 4);

  // adjacency words for own q-row (also early)
  int node = half*128 + w*32 + l31;
  uint4 m0 = *(const uint4*)(mask + node * 8);
  uint4 m1 = *(const uint4*)(mask + node * 8 + 4);

  // stage W: b128 loads + b128 LDS writes (6 iterations)
  const uint4* WtH4 = (const uint4*)WtH;
  #pragma unroll
  for (int g4 = 0; g4 < 6; ++g4) {
    int g = t + g4 * 256;              // g < 1536 = 96*16
    uint4 v = WtH4[g];
    int row = g >> 4, c4 = (g & 15) * 4;
    *(uint4*)&wLds[row*68 + c4] = v;
  }
  if (t < 128) woS[t] = woT2[t];
  if (t < 8) boS[t] = bo[t];

  // accumulator init
  f32x16 aq, ak0, av0, ak1, av1;
  #pragma unroll
  for (int r = 0; r < 16; ++r) aq[r] = bias[(r & 3) + 8*(r >> 2) + 4*hi];
  {
    float bk_ = bias[32 + l31], bv_ = bias[64 + l31];
    #pragma unroll
    for (int r = 0; r < 16; ++r) { ak0[r]=bk_; av0[r]=bv_; ak1[r]=bk_; av1[r]=bv_; }
  }
  u32 mw8[8] = { m0.x, m0.y, m0.z, m0.w, m1.x, m1.y, m1.z, m1.w };
  #pragma unroll
  for (int i = 0; i < 8; ++i) mw8[i] = hi ? (mw8[i] >> 4) : mw8[i];

  __syncthreads();                     // wLds ready

  // ---- QKV: K=16 mfma, 8 steps, dual tile, 1-deep x prefetch ----
  #pragma unroll
  for (int ks = 0; ks < 8; ++ks) {
    float4 xn0a, xn0b, xn1a, xn1b;
    if (ks < 7) {                      // issue next loads before this step's chain
      xn0a = *(const float4*)(xr0 + (ks + 1) * 16);
      xn0b = *(const float4*)(xr0 + (ks + 1) * 16 + 4);
      xn1a = *(const float4*)(xr1 + (ks + 1) * 16);
      xn1b = *(const float4*)(xr1 + (ks + 1) * 16 + 4);
    }
    h8 f0 = bch8(make_uint4(bcu(__builtin_amdgcn_cvt_pkrtz(xc0a.x, xc0a.y)),
                            bcu(__builtin_amdgcn_cvt_pkrtz(xc0a.z, xc0a.w)),
                            bcu(__builtin_amdgcn_cvt_pkrtz(xc0b.x, xc0b.y)),
                            bcu(__builtin_amdgcn_cvt_pkrtz(xc0b.z, xc0b.w))));
    h8 f1 = bch8(make_uint4(bcu(__builtin_amdgcn_cvt_pkrtz(xc1a.x, xc1a.y)),
                            bcu(__builtin_amdgcn_cvt_pkrtz(xc1a.z, xc1a.w)),
                            bcu(__builtin_amdgcn_cvt_pkrtz(xc1b.x, xc1b.y)),
                            bcu(__builtin_amdgcn_cvt_pkrtz(xc1b.z, xc1b.w))));
    h8 wk = bch8(*(const uint4*)&wLds[(32 + l31)*68 + ks*8 + 4*hi]);
    h8 wv = bch8(*(const uint4*)&wLds[(64 + l31)*68 + ks*8 + 4*hi]);
    h8 wq = bch8(*(const uint4*)&wLds[l31*68 + ks*8 + 4*hi]);
    ak0 = mfma16(f0, wk, ak0);         // k: lane=hd-col, regs=node-rows
    ak1 = mfma16(f1, wk, ak1);
    av0 = mfma16(f0, wv, av0);
    av1 = mfma16(f1, wv, av1);
    aq  = mfma16(wq, half ? f1 : f0, aq);  // q^T of own tile: lane=node, regs=hd
    xc0a = xn0a; xc0b = xn0b; xc1a = xn1a; xc1b = xn1b;
  }
  #pragma unroll
  for (int r = 0; r < 16; ++r) {
    int rc = (r & 3) + 8*(r >> 2) + 4*hi;
    int n0 = w*32 + rc, n1 = n0 + 128;
    kS[n0 * 36 + l31] = (__fp16)ak0[r];
    kS[n1 * 36 + l31] = (__fp16)ak1[r];
    vt32[l31 * 264 + n0] = (__fp16)av0[r];
    vt32[l31 * 264 + n1] = (__fp16)av1[r];
  }
  // Q B-frags for K=8 QK^T, PRE-SCALED by sc2 = (1/sqrt 8)*log2(e)
  const float sc2 = 0.51006977f;
  h4 Qf[4];
  #pragma unroll
  for (int h = 0; h < 4; ++h) {
    h2v qa = __builtin_amdgcn_cvt_pkrtz(aq[4*h]*sc2,     aq[4*h + 1]*sc2);
    h2v qb = __builtin_amdgcn_cvt_pkrtz(aq[4*h + 2]*sc2, aq[4*h + 3]*sc2);
    Qf[h] = __builtin_shufflevector(qa, qb, 0, 1, 2, 3);
  }
  __syncthreads();                     // kS/vt32 ready (wLds now dead -> oS alias)

  // ---- attention: QK^T K=8 with mask-as-C; PV K=16 via permlane32_swap --------
  const h2v one2 = bch2(0x3C003C00u);  // (1.0h, 1.0h)
  f32x16 accO[4] = { fzero(), fzero(), fzero(), fzero() };
  float lp[4] = { 0.f, 0.f, 0.f, 0.f };
  #pragma unroll
  for (int kt = 0; kt < 8; ++kt) {
    u32 mwh = mw8[kt];
    f32x16 mbvV;                       // C operand: anchor -8 or mask -1e30
    #pragma unroll
    for (int r = 0; r < 16; ++r) {
      int bp = (r & 3) + 8*(r >> 2);
      mbvV[r] = ((mwh >> bp) & 1u) ? -8.0f : -1e30f;
    }
    u32 pw[4][8];
    #pragma unroll
    for (int h = 0; h < 4; ++h) {
      h4 Kf = bch4(*(const uint2*)&kS[(kt*32 + l31)*36 + 8*h + 4*hi]);
      f32x16 T = mfma8(Kf, Qf[h], mbvV);   // T[r] = s*sc2 + (-8 | -1e30)
      #pragma unroll
      for (int j = 0; j < 8; ++j) {
        float p0 = __builtin_amdgcn_exp2f(T[2*j]);
        float p1 = __builtin_amdgcn_exp2f(T[2*j+1]);
        pw[h][j] = bcu(__builtin_amdgcn_cvt_pkrtz(p0, p1));
        lp[h] = dot2(bch2(pw[h][j]), one2, lp[h]);   // l-sum on packed pairs
      }
    }
    // V^T A-frags (K=16): row=hd, k = kk16*16 + 8hi + j -> b128, shared by heads
    h8 va0 = bch8(*(const uint4*)&vt32[l31*264 + kt*32 + 8*hi]);
    h8 va1 = bch8(*(const uint4*)&vt32[l31*264 + kt*32 + 16 + 8*hi]);
    __builtin_amdgcn_s_setprio(1);
    #pragma unroll
    for (int h = 0; h < 4; ++h) {
      // B-frag build: {B0,B2}=swap(w0,w2), {B1,B3}=swap(w1,w3)
      u32 a0 = pw[h][0], a1 = pw[h][1], a2 = pw[h][2], a3 = pw[h][3];
      asm("v_permlane32_swap_b32 %0, %1" : "+v"(a0), "+v"(a2));
      asm("v_permlane32_swap_b32 %0, %1" : "+v"(a1), "+v"(a3));
      accO[h] = mfma16(va0, bch8(make_uint4(a0, a1, a2, a3)), accO[h]);
      u32 c0 = pw[h][4], c1 = pw[h][5], c2 = pw[h][6], c3 = pw[h][7];
      asm("v_permlane32_swap_b32 %0, %1" : "+v"(c0), "+v"(c2));
      asm("v_permlane32_swap_b32 %0, %1" : "+v"(c1), "+v"(c3));
      accO[h] = mfma16(va1, bch8(make_uint4(c0, c1, c2, c3)), accO[h]);
    }
    __builtin_amdgcn_s_setprio(0);
  }
  // epilogue: head h output lives in accO[h] regs 4h..4h+3 (col q=l31)
  #pragma unroll
  for (int h = 0; h < 4; ++h) {
    float lq = lp[h] + __shfl_xor(lp[h], 32);
    float inv = 1.0f / lq;
    h2v o0 = __builtin_amdgcn_cvt_pkrtz(accO[h][4*h]*inv,   accO[h][4*h+1]*inv);
    h2v o1 = __builtin_amdgcn_cvt_pkrtz(accO[h][4*h+2]*inv, accO[h][4*h+3]*inv);
    *(uint2*)&oS[(w*32 + l31)*36 + 8*h + 4*hi] = make_uint2(bcu(o0), bcu(o1));
  }
  __syncthreads();

  // ---- proj: 2 threads per row; b64 oS reads; out = oS @ Wo + bo ----
  int pr = t >> 1, d4 = (t & 1) * 4;
  float r4[4] = { boS[d4], boS[d4+1], boS[d4+2], boS[d4+3] };
  #pragma unroll
  for (int pp = 0; pp < 8; ++pp) {
    uint2 oo = *(const uint2*)&oS[pr*36 + 4*pp];   // 72B row stride: 8-aligned
    h2v o2a = bch2(oo.x), o2b = bch2(oo.y);
    #pragma unroll
    for (int d = 0; d < 4; ++d) {
      r4[d] = dot2(o2a, bch2(woS[(d4 + d)*16 + 2*pp]),     r4[d]);
      r4[d] = dot2(o2b, bch2(woS[(d4 + d)*16 + 2*pp + 1]), r4[d]);
    }
  }
  float4 o = { r4[0], r4[1], r4[2], r4[3] };
  *(float4*)(out + ((size_t)b * NNODE + half*128 + pr) * DD + d4) = o;
}

extern "C" void kernel_launch(void* const* d_in, const int* in_sizes, int n_in,
                              void* d_out, int out_size, void* d_ws, size_t ws_size,
                              hipStream_t stream)
{
  const float* x  = (const float*)d_in[0];
  const int*   ei = (const int*)d_in[1];
  const float* Wq = (const float*)d_in[2];
  const float* bq = (const float*)d_in[3];
  const float* Wk = (const float*)d_in[4];
  const float* bk = (const float*)d_in[5];
  const float* Wv = (const float*)d_in[6];
  const float* bv = (const float*)d_in[7];
  const float* Wo = (const float*)d_in[8];
  const float* bo = (const float*)d_in[9];
  int E = in_sizes[1] / 2;

  char* ws = (char*)d_ws;
  u32*   mask = (u32*)(ws + 0);                 // 8 KB
  u32*   WtH  = (u32*)(ws + 8192);              // 24 KB: W^T[c][kp] f16-packed
  float* bias = (float*)(ws + 32768);           // 384 B
  u32*   woT2 = (u32*)(ws + 33280);             // 512 B

  hipMemsetAsync(mask, 0, NNODE * 8 * sizeof(u32), stream);
  int prep_work = (96*64 > E) ? 96*64 : E;
  prep_kernel<<<(prep_work + 255)/256, 256, 0, stream>>>(
      Wq, bq, Wk, bk, Wv, bv, Wo, ei, E, mask, WtH, bias, woT2);
  fused_kernel<<<NB * 2, 256, 0, stream>>>(x, WtH, bias, mask, woT2, bo,
                                           (float*)d_out);
}

// Round 24
// 34.229 us; speedup vs baseline: 1.4477x; 1.0123x over previous
//
#include <hip/hip_runtime.h>

typedef unsigned int u32;
typedef __fp16 h2v __attribute__((ext_vector_type(2)));
typedef __fp16 h4 __attribute__((ext_vector_type(4)));
typedef __fp16 h8 __attribute__((ext_vector_type(8)));
typedef float f32x16 __attribute__((ext_vector_type(16)));

#define NB 256
#define NNODE 256
#define FF 128
#define DD 8
#define HDIM 32

__device__ __forceinline__ float dot2(h2v a, h2v b, float c) {
  return __builtin_amdgcn_fdot2(a, b, c, false);
}
__device__ __forceinline__ h2v bch2(u32 u) { return __builtin_bit_cast(h2v, u); }
__device__ __forceinline__ h4 bch4(uint2 u) { return __builtin_bit_cast(h4, u); }
__device__ __forceinline__ h8 bch8(uint4 u) { return __builtin_bit_cast(h8, u); }
__device__ __forceinline__ u32 bcu(h2v v) { return __builtin_bit_cast(u32, v); }
__device__ __forceinline__ f32x16 fzero() {
  f32x16 z;
  #pragma unroll
  for (int r = 0; r < 16; ++r) z[r] = 0.f;
  return z;
}
__device__ __forceinline__ f32x16 mfma8(h4 a, h4 b, f32x16 c) {
  return __builtin_amdgcn_mfma_f32_32x32x8f16(a, b, c, 0, 0, 0);
}
__device__ __forceinline__ f32x16 mfma16(h8 a, h8 b, f32x16 c) {
  return __builtin_amdgcn_mfma_f32_32x32x16_f16(a, b, c, 0, 0, 0);
}

// -------- prep: W pack + bias + woT2 + edge scatter (mask pre-zeroed) ----------
__global__ __launch_bounds__(256) void prep_kernel(
    const float* __restrict__ Wq, const float* __restrict__ bq,
    const float* __restrict__ Wk, const float* __restrict__ bk,
    const float* __restrict__ Wv, const float* __restrict__ bv,
    const float* __restrict__ Wo, const int* __restrict__ eidx, int E,
    u32* __restrict__ mask, u32* __restrict__ WtH, float* __restrict__ bias,
    u32* __restrict__ woT2)
{
  int g = blockIdx.x * 256 + threadIdx.x;
  if (g < 96 * 64) {                 // WtH[c][kp]: pack W[2kp][c], W[2kp+1][c]
    int c = g >> 6, f = (g & 63) * 2;
    const float* W = (c < 32) ? Wq : ((c < 64) ? Wk : Wv);
    int cc = c & 31;
    WtH[g] = bcu(__builtin_amdgcn_cvt_pkrtz(W[f*HDIM + cc], W[(f+1)*HDIM + cc]));
  }
  if (g < 96) {
    const float* bb = (g < 32) ? bq : ((g < 64) ? bk : bv);
    bias[g] = bb[g & 31];
  }
  if (g < 128) {                     // woT2[d][p] = pack Wo[2p][d], Wo[2p+1][d]
    int d = g >> 4, p = g & 15;
    woT2[g] = bcu(__builtin_amdgcn_cvt_pkrtz(Wo[(2*p)*DD + d], Wo[(2*p+1)*DD + d]));
  }
  if (g < E) {
    int r = eidx[g], c = eidx[E + g];
    atomicOr(&mask[r*8 + (c >> 5)], 1u << (c & 31));
  }
}

// -------- fused: 2 blocks/batch (XCD-paired); K=16 QKV/PV; mask-as-C QK^T ------
__global__ __launch_bounds__(256, 2) void fused_kernel(
    const float* __restrict__ x, const u32* __restrict__ WtH,
    const float* __restrict__ bias, const u32* __restrict__ mask,
    const u32* __restrict__ woT2, const float* __restrict__ bo,
    float* __restrict__ out)
{
  __shared__ u32 wLds[96 * 68];        // 26.1 KB; stride 68 u32 (272B, 16B-aligned)
  __shared__ __fp16 kS[NNODE * 36];    // 18 KB
  __shared__ __fp16 vt32[32 * 264];    // 16.9 KB; stride 264 f16 (528B)
  __shared__ u32 woS[128];
  __shared__ float boS[8];
  __fp16* oS = (__fp16*)wLds;          // 9 KB alias; wLds dead after QKV phase

  int t = threadIdx.x, lane = t & 63, w = t >> 6;   // 4 waves
  int l31 = lane & 31, hi = lane >> 5;
  // XCD pairing: halves of batch b are bids b and b+256 -> same XCD (b%8)
  int b = blockIdx.x & 255, half = blockIdx.x >> 8;

  // ---- issue x ks=0 loads FIRST (independent of LDS; barrier would fence them)
  const float* xr0 = x + ((size_t)b * NNODE + w*32 + l31) * FF + 8 * hi;
  const float* xr1 = xr0 + (size_t)128 * FF;
  float4 xc0a = *(const float4*)(xr0),     xc0b = *(const float4*)(xr0 + 4);
  float4 xc1a = *(const float4*)(xr1),     xc1b = *(const float4*)(xr1 + 4);

  // adjacency words for own q-row (also early)
  int node = half*128 + w*32 + l31;
  uint4 m0 = *(const uint4*)(mask + node * 8);
  uint4 m1 = *(const uint4*)(mask + node * 8 + 4);

  // stage W: b128 loads + b128 LDS writes (6 iterations)
  const uint4* WtH4 = (const uint4*)WtH;
  #pragma unroll
  for (int g4 = 0; g4 < 6; ++g4) {
    int g = t + g4 * 256;              // g < 1536 = 96*16
    uint4 v = WtH4[g];
    int row = g >> 4, c4 = (g & 15) * 4;
    *(uint4*)&wLds[row*68 + c4] = v;
  }
  if (t < 128) woS[t] = woT2[t];
  if (t < 8) boS[t] = bo[t];

  // accumulator init
  f32x16 aq, ak0, av0, ak1, av1;
  #pragma unroll
  for (int r = 0; r < 16; ++r) aq[r] = bias[(r & 3) + 8*(r >> 2) + 4*hi];
  {
    float bk_ = bias[32 + l31], bv_ = bias[64 + l31];
    #pragma unroll
    for (int r = 0; r < 16; ++r) { ak0[r]=bk_; av0[r]=bv_; ak1[r]=bk_; av1[r]=bv_; }
  }
  u32 mw8[8] = { m0.x, m0.y, m0.z, m0.w, m1.x, m1.y, m1.z, m1.w };
  #pragma unroll
  for (int i = 0; i < 8; ++i) mw8[i] = hi ? (mw8[i] >> 4) : mw8[i];

  __syncthreads();                     // wLds ready

  // ---- QKV: K=16 mfma, 8 steps, dual tile, 1-deep x prefetch ----
  #pragma unroll
  for (int ks = 0; ks < 8; ++ks) {
    float4 xn0a, xn0b, xn1a, xn1b;
    if (ks < 7) {                      // issue next loads before this step's chain
      xn0a = *(const float4*)(xr0 + (ks + 1) * 16);
      xn0b = *(const float4*)(xr0 + (ks + 1) * 16 + 4);
      xn1a = *(const float4*)(xr1 + (ks + 1) * 16);
      xn1b = *(const float4*)(xr1 + (ks + 1) * 16 + 4);
    }
    h8 f0 = bch8(make_uint4(bcu(__builtin_amdgcn_cvt_pkrtz(xc0a.x, xc0a.y)),
                            bcu(__builtin_amdgcn_cvt_pkrtz(xc0a.z, xc0a.w)),
                            bcu(__builtin_amdgcn_cvt_pkrtz(xc0b.x, xc0b.y)),
                            bcu(__builtin_amdgcn_cvt_pkrtz(xc0b.z, xc0b.w))));
    h8 f1 = bch8(make_uint4(bcu(__builtin_amdgcn_cvt_pkrtz(xc1a.x, xc1a.y)),
                            bcu(__builtin_amdgcn_cvt_pkrtz(xc1a.z, xc1a.w)),
                            bcu(__builtin_amdgcn_cvt_pkrtz(xc1b.x, xc1b.y)),
                            bcu(__builtin_amdgcn_cvt_pkrtz(xc1b.z, xc1b.w))));
    h8 wk = bch8(*(const uint4*)&wLds[(32 + l31)*68 + ks*8 + 4*hi]);
    h8 wv = bch8(*(const uint4*)&wLds[(64 + l31)*68 + ks*8 + 4*hi]);
    h8 wq = bch8(*(const uint4*)&wLds[l31*68 + ks*8 + 4*hi]);
    ak0 = mfma16(f0, wk, ak0);         // k: lane=hd-col, regs=node-rows
    ak1 = mfma16(f1, wk, ak1);
    av0 = mfma16(f0, wv, av0);
    av1 = mfma16(f1, wv, av1);
    aq  = mfma16(wq, half ? f1 : f0, aq);  // q^T of own tile: lane=node, regs=hd
    xc0a = xn0a; xc0b = xn0b; xc1a = xn1a; xc1b = xn1b;
  }
  // kS scatter (rows differ per reg -> scalar b16 writes)
  #pragma unroll
  for (int r = 0; r < 16; ++r) {
    int rc = (r & 3) + 8*(r >> 2) + 4*hi;
    int n0 = w*32 + rc;
    kS[n0 * 36 + l31] = (__fp16)ak0[r];
    kS[(n0 + 128) * 36 + l31] = (__fp16)ak1[r];
  }
  // vt32 scatter: reg-quad q -> 4 CONSECUTIVE nodes -> pack as ds_write_b64
  #pragma unroll
  for (int q = 0; q < 4; ++q) {
    int nb = w*32 + 8*q + 4*hi;        // base node of this quad (8B-aligned elem)
    uint2 p0 = make_uint2(bcu(__builtin_amdgcn_cvt_pkrtz(av0[4*q],   av0[4*q+1])),
                          bcu(__builtin_amdgcn_cvt_pkrtz(av0[4*q+2], av0[4*q+3])));
    *(uint2*)&vt32[l31*264 + nb] = p0;
    uint2 p1 = make_uint2(bcu(__builtin_amdgcn_cvt_pkrtz(av1[4*q],   av1[4*q+1])),
                          bcu(__builtin_amdgcn_cvt_pkrtz(av1[4*q+2], av1[4*q+3])));
    *(uint2*)&vt32[l31*264 + nb + 128] = p1;
  }
  // Q B-frags for K=8 QK^T, PRE-SCALED by sc2 = (1/sqrt 8)*log2(e)
  const float sc2 = 0.51006977f;
  h4 Qf[4];
  #pragma unroll
  for (int h = 0; h < 4; ++h) {
    h2v qa = __builtin_amdgcn_cvt_pkrtz(aq[4*h]*sc2,     aq[4*h + 1]*sc2);
    h2v qb = __builtin_amdgcn_cvt_pkrtz(aq[4*h + 2]*sc2, aq[4*h + 3]*sc2);
    Qf[h] = __builtin_shufflevector(qa, qb, 0, 1, 2, 3);
  }
  __syncthreads();                     // kS/vt32 ready (wLds now dead -> oS alias)

  // ---- attention: QK^T K=8 with mask-as-C; PV K=16 via permlane32_swap --------
  const h2v one2 = bch2(0x3C003C00u);  // (1.0h, 1.0h)
  f32x16 accO[4] = { fzero(), fzero(), fzero(), fzero() };
  float lp[4] = { 0.f, 0.f, 0.f, 0.f };
  #pragma unroll
  for (int kt = 0; kt < 8; ++kt) {
    u32 mwh = mw8[kt];
    f32x16 mbvV;                       // C operand: anchor -8 or mask -1e30
    #pragma unroll
    for (int r = 0; r < 16; ++r) {
      int bp = (r & 3) + 8*(r >> 2);
      mbvV[r] = ((mwh >> bp) & 1u) ? -8.0f : -1e30f;
    }
    u32 pw[4][8];
    #pragma unroll
    for (int h = 0; h < 4; ++h) {
      h4 Kf = bch4(*(const uint2*)&kS[(kt*32 + l31)*36 + 8*h + 4*hi]);
      f32x16 T = mfma8(Kf, Qf[h], mbvV);   // T[r] = s*sc2 + (-8 | -1e30)
      #pragma unroll
      for (int j = 0; j < 8; ++j) {
        float p0 = __builtin_amdgcn_exp2f(T[2*j]);
        float p1 = __builtin_amdgcn_exp2f(T[2*j+1]);
        pw[h][j] = bcu(__builtin_amdgcn_cvt_pkrtz(p0, p1));
        lp[h] = dot2(bch2(pw[h][j]), one2, lp[h]);   // l-sum on packed pairs
      }
    }
    // V^T A-frags (K=16): row=hd, k = kk16*16 + 8hi + j -> b128, shared by heads
    h8 va0 = bch8(*(const uint4*)&vt32[l31*264 + kt*32 + 8*hi]);
    h8 va1 = bch8(*(const uint4*)&vt32[l31*264 + kt*32 + 16 + 8*hi]);
    __builtin_amdgcn_s_setprio(1);
    #pragma unroll
    for (int h = 0; h < 4; ++h) {
      // B-frag build: {B0,B2}=swap(w0,w2), {B1,B3}=swap(w1,w3)
      u32 a0 = pw[h][0], a1 = pw[h][1], a2 = pw[h][2], a3 = pw[h][3];
      asm("v_permlane32_swap_b32 %0, %1" : "+v"(a0), "+v"(a2));
      asm("v_permlane32_swap_b32 %0, %1" : "+v"(a1), "+v"(a3));
      accO[h] = mfma16(va0, bch8(make_uint4(a0, a1, a2, a3)), accO[h]);
      u32 c0 = pw[h][4], c1 = pw[h][5], c2 = pw[h][6], c3 = pw[h][7];
      asm("v_permlane32_swap_b32 %0, %1" : "+v"(c0), "+v"(c2));
      asm("v_permlane32_swap_b32 %0, %1" : "+v"(c1), "+v"(c3));
      accO[h] = mfma16(va1, bch8(make_uint4(c0, c1, c2, c3)), accO[h]);
    }
    __builtin_amdgcn_s_setprio(0);
  }
  // epilogue: head h output lives in accO[h] regs 4h..4h+3 (col q=l31)
  #pragma unroll
  for (int h = 0; h < 4; ++h) {
    float lq = lp[h] + __shfl_xor(lp[h], 32);
    float inv = 1.0f / lq;
    h2v o0 = __builtin_amdgcn_cvt_pkrtz(accO[h][4*h]*inv,   accO[h][4*h+1]*inv);
    h2v o1 = __builtin_amdgcn_cvt_pkrtz(accO[h][4*h+2]*inv, accO[h][4*h+3]*inv);
    *(uint2*)&oS[(w*32 + l31)*36 + 8*h + 4*hi] = make_uint2(bcu(o0), bcu(o1));
  }
  __syncthreads();

  // ---- proj: 2 threads per row; b64 oS reads; out = oS @ Wo + bo ----
  int pr = t >> 1, d4 = (t & 1) * 4;
  float r4[4] = { boS[d4], boS[d4+1], boS[d4+2], boS[d4+3] };
  #pragma unroll
  for (int pp = 0; pp < 8; ++pp) {
    uint2 oo = *(const uint2*)&oS[pr*36 + 4*pp];   // 72B row stride: 8-aligned
    h2v o2a = bch2(oo.x), o2b = bch2(oo.y);
    #pragma unroll
    for (int d = 0; d < 4; ++d) {
      r4[d] = dot2(o2a, bch2(woS[(d4 + d)*16 + 2*pp]),     r4[d]);
      r4[d] = dot2(o2b, bch2(woS[(d4 + d)*16 + 2*pp + 1]), r4[d]);
    }
  }
  float4 o = { r4[0], r4[1], r4[2], r4[3] };
  *(float4*)(out + ((size_t)b * NNODE + half*128 + pr) * DD + d4) = o;
}

extern "C" void kernel_launch(void* const* d_in, const int* in_sizes, int n_in,
                              void* d_out, int out_size, void* d_ws, size_t ws_size,
                              hipStream_t stream)
{
  const float* x  = (const float*)d_in[0];
  const int*   ei = (const int*)d_in[1];
  const float* Wq = (const float*)d_in[2];
  const float* bq = (const float*)d_in[3];
  const float* Wk = (const float*)d_in[4];
  const float* bk = (const float*)d_in[5];
  const float* Wv = (const float*)d_in[6];
  const float* bv = (const float*)d_in[7];
  const float* Wo = (const float*)d_in[8];
  const float* bo = (const float*)d_in[9];
  int E = in_sizes[1] / 2;

  char* ws = (char*)d_ws;
  u32*   mask = (u32*)(ws + 0);                 // 8 KB
  u32*   WtH  = (u32*)(ws + 8192);              // 24 KB: W^T[c][kp] f16-packed
  float* bias = (float*)(ws + 32768);           // 384 B
  u32*   woT2 = (u32*)(ws + 33280);             // 512 B

  hipMemsetAsync(mask, 0, NNODE * 8 * sizeof(u32), stream);
  int prep_work = (96*64 > E) ? 96*64 : E;
  prep_kernel<<<(prep_work + 255)/256, 256, 0, stream>>>(
      Wq, bq, Wk, bk, Wv, bv, Wo, ei, E, mask, WtH, bias, woT2);
  fused_kernel<<<NB * 2, 256, 0, stream>>>(x, WtH, bias, mask, woT2, bo,
                                           (float*)d_out);
}